// Round 15
// baseline (494.636 us; speedup 1.0000x reference)
//
#include <hip/hip_runtime.h>

typedef __attribute__((ext_vector_type(8))) short s16x8;
typedef __attribute__((ext_vector_type(4))) float f32x4;

#define TN 288

__device__ __forceinline__ unsigned short f2bf(float f) {
  union { float f; unsigned u; } v; v.f = f;
  unsigned r = v.u + 0x7fffu + ((v.u >> 16) & 1u);
  return (unsigned short)(r >> 16);
}
__device__ __forceinline__ float bf2f(unsigned short u) {
  union { float f; unsigned u; } v; v.u = ((unsigned)u) << 16;
  return v.f;
}
__device__ __forceinline__ unsigned lds_addr(const void* p) {
  return (unsigned)(unsigned long long)(const __attribute__((address_space(3))) char*)p;
}
__device__ __forceinline__ void async_copy16(unsigned short* lds, const unsigned short* g) {
  __builtin_amdgcn_global_load_lds(
      (const __attribute__((address_space(1))) unsigned int*)g,
      (__attribute__((address_space(3))) unsigned int*)lds, 16, 0, 0);
}

// ---------------- fused prep: onehot + weight casts + packs (1 launch) ----
__device__ __forceinline__ void pack_body(const float* __restrict__ W,
    unsigned short* __restrict__ out, int N, long t) {
  int lr = (int)(t & 15);
  int lg = (int)((t >> 4) & 3);
  long g6 = t >> 6;
  int nt = N >> 4;
  int n16 = (int)(g6 % nt);
  int kb = (int)(g6 / nt) << 5;
  int k = kb + lg * 8;
  int col = n16 * 16 + lr;
  s16x8 v;
#pragma unroll
  for (int j = 0; j < 8; ++j) v[j] = (short)f2bf(W[(size_t)(k + j) * N + col]);
  *(s16x8*)(out + t * 8) = v;
}

__global__ __launch_bounds__(256) void prep_kernel(const int* __restrict__ pi,
    const float* __restrict__ I_mat, const float* __restrict__ ohW,
    const float* __restrict__ ohb, float* __restrict__ onehot,
    const float* __restrict__ Wv, const float* __restrict__ Wk,
    const float* __restrict__ Wq, unsigned short* __restrict__ Wv_b,
    unsigned short* __restrict__ Wk_b, unsigned short* __restrict__ Wq_b,
    const float* __restrict__ Wo, const float* __restrict__ W1,
    const float* __restrict__ W2, unsigned short* __restrict__ Wop,
    unsigned short* __restrict__ W1p, unsigned short* __restrict__ W2p) {
  int b = blockIdx.x, tid = threadIdx.x;
  if (b < 512) {
    int t = b;
    int r = (pi[0] + t) % TN;
    float acc0 = ohb[tid], acc1 = ohb[tid + 256];
    const float* Ir = I_mat + (size_t)r * TN;
    for (int j = 0; j < TN; ++j) {
      float iv = Ir[j];
      acc0 += iv * ohW[(size_t)j * 512 + tid];
      acc1 += iv * ohW[(size_t)j * 512 + tid + 256];
    }
    onehot[(size_t)t * 512 + tid] = acc0;
    onehot[(size_t)t * 512 + tid + 256] = acc1;
  } else if (b < 640) {
    pack_body(Wo, Wop, 512, (long)(b - 512) * 256 + tid);
  } else if (b < 1152) {
    pack_body(W1, W1p, 2048, (long)(b - 640) * 256 + tid);
  } else if (b < 1664) {
    pack_body(W2, W2p, 512, (long)(b - 1152) * 256 + tid);
  } else {
    int which = b - 1664;
    const float* src = which == 0 ? Wv : (which == 1 ? Wk : Wq);
    unsigned short* dst = which == 0 ? Wv_b : (which == 1 ? Wk_b : Wq_b);
    float sc = which == 2 ? 0.06375871424f : 1.f;  // Wq: 1/sqrt(512)*log2(e)
#pragma unroll
    for (int j = 0; j < 4; ++j) {
      int i = tid * 16 + j * 4;
      float4 f = *(const float4*)(src + i);
      unsigned lo = (unsigned)f2bf(f.x * sc) | ((unsigned)f2bf(f.y * sc) << 16);
      unsigned hi = (unsigned)f2bf(f.z * sc) | ((unsigned)f2bf(f.w * sc) << 16);
      *(uint2*)(dst + i) = make_uint2(lo, hi);
    }
  }
}

// ---------------- fused projection GEMMs: grid 12288, which = bid>>12 -----
// which 0: V packed into MFMA-fragment order:
//   vP[(n*8+h)*32768 + ((c*16 + ks*4 + fj)*64 + l)*8 + j] =
//     V[t = c*128+ks*32+(l>>4)*8+j][d = fj*16+(l&15)]   (per (n,h))
// which 1: K row-major; which 2: Q (+onehot), row-major
__global__ __launch_bounds__(256) void proj_all(
    const float* __restrict__ value, const float* __restrict__ key_in,
    const float* __restrict__ query, const unsigned short* __restrict__ Wv_b,
    const unsigned short* __restrict__ Wk_b, const unsigned short* __restrict__ Wq_b,
    const float* __restrict__ onehot, unsigned short* __restrict__ vP,
    unsigned short* __restrict__ k_p, unsigned short* __restrict__ q_p) {
  __shared__ unsigned short As[64][40];
  __shared__ unsigned short Bs[64][40];   // Bs[col][k]
  __shared__ unsigned short Cs[64][72];   // V-pack bounce
  const int which = blockIdx.x >> 12;
  const int mb = blockIdx.x & 4095;
  const float* A = which == 0 ? value : (which == 1 ? key_in : query);
  const unsigned short* B = which == 0 ? Wv_b : (which == 1 ? Wk_b : Wq_b);
  unsigned short* C = which == 0 ? vP : (which == 1 ? k_p : q_p);
  const bool qin = (which == 2);
  const int m0 = mb * 64;
  const int tid = threadIdx.x, w = tid >> 6, l = tid & 63, lr = l & 15, lg = l >> 4;
  const int wr = (w >> 1) * 32, wc = (w & 1) * 32;
  const int aRow = (tid * 8) >> 5, aK = (tid * 8) & 31;
  const int bK = (tid * 8) >> 6, bCol = (tid * 8) & 63;
  f32x4 acc[2][2] = {};
  for (int kb = 0; kb < 64; kb += 32) {
    size_t fl = (size_t)(m0 + aRow) * 64 + kb + aK;
    float4 f0 = *(const float4*)(A + fl);
    float4 f1 = *(const float4*)(A + fl + 4);
    if (qin) {
      const float* oh = onehot + (fl & 262143);
      float4 o0 = *(const float4*)(oh);
      float4 o1 = *(const float4*)(oh + 4);
      f0.x += o0.x; f0.y += o0.y; f0.z += o0.z; f0.w += o0.w;
      f1.x += o1.x; f1.y += o1.y; f1.z += o1.z; f1.w += o1.w;
    }
    s16x8 av;
    av[0] = (short)f2bf(f0.x); av[1] = (short)f2bf(f0.y);
    av[2] = (short)f2bf(f0.z); av[3] = (short)f2bf(f0.w);
    av[4] = (short)f2bf(f1.x); av[5] = (short)f2bf(f1.y);
    av[6] = (short)f2bf(f1.z); av[7] = (short)f2bf(f1.w);
    *(s16x8*)&As[aRow][aK] = av;
    s16x8 bv = *(const s16x8*)(B + (size_t)(kb + bK) * 64 + bCol);
#pragma unroll
    for (int j = 0; j < 8; ++j) Bs[bCol + j][bK] = (unsigned short)bv[j];
    __syncthreads();
    s16x8 af0 = *(const s16x8*)&As[wr + lr][lg * 8];
    s16x8 af1 = *(const s16x8*)&As[wr + 16 + lr][lg * 8];
    s16x8 bf0 = *(const s16x8*)&Bs[wc + lr][lg * 8];
    s16x8 bf1 = *(const s16x8*)&Bs[wc + 16 + lr][lg * 8];
    acc[0][0] = __builtin_amdgcn_mfma_f32_16x16x32_bf16(af0, bf0, acc[0][0], 0, 0, 0);
    acc[0][1] = __builtin_amdgcn_mfma_f32_16x16x32_bf16(af0, bf1, acc[0][1], 0, 0, 0);
    acc[1][0] = __builtin_amdgcn_mfma_f32_16x16x32_bf16(af1, bf0, acc[1][0], 0, 0, 0);
    acc[1][1] = __builtin_amdgcn_mfma_f32_16x16x32_bf16(af1, bf1, acc[1][1], 0, 0, 0);
    __syncthreads();
  }
  if (which != 0) {
#pragma unroll
    for (int fi = 0; fi < 2; ++fi)
#pragma unroll
      for (int fj = 0; fj < 2; ++fj)
#pragma unroll
        for (int r = 0; r < 4; ++r) {
          int row = m0 + wr + fi * 16 + lg * 4 + r;
          int col = wc + fj * 16 + lr;
          C[(size_t)row * 64 + col] = f2bf(acc[fi][fj][r]);
        }
  } else {
#pragma unroll
    for (int fi = 0; fi < 2; ++fi)
#pragma unroll
      for (int fj = 0; fj < 2; ++fj)
#pragma unroll
        for (int r = 0; r < 4; ++r)
          Cs[wr + fi * 16 + lg * 4 + r][wc + fj * 16 + lr] = f2bf(acc[fi][fj][r]);
    __syncthreads();
    // rows m0..m0+63 encode (n*512+t)*8+h: t = t0 + r_local/8, h = r_local&7
    int nIdx = m0 >> 12, t0 = (m0 >> 3) & 511;
    int cc = t0 >> 7, ksv = (t0 >> 5) & 3, lgv = (t0 >> 3) & 3;
#pragma unroll
    for (int it = 0; it < 2; ++it) {
      int p = tid + it * 256;
      int hh = p >> 6, d = p & 63;
      s16x8 vv;
#pragma unroll
      for (int j = 0; j < 8; ++j) vv[j] = (short)Cs[j * 8 + hh][d];
      size_t dst = ((size_t)(nIdx * 8 + hh)) * 32768 +
                   (size_t)(((cc * 16 + ksv * 4 + (d >> 4)) * 64) + lgv * 16 + (d & 15)) * 8;
      *(s16x8*)(C + dst) = vv;
    }
  }
}

// ---------------- big GEMM: BK=64, XCD-swizzled 1D grid, B 2-deep prefetch
// RES: add bf16 residual (same ldc) in epilogue
template<bool RELU, bool OUTBF, bool RES>
__global__ __launch_bounds__(256) void gemmF(
    const unsigned short* __restrict__ A, int lda,
    const unsigned short* __restrict__ Bp, int ldbp, int nOff,
    const float* __restrict__ bias, void* __restrict__ Cout,
    const unsigned short* __restrict__ resid, int ldc,
    int M, int K, int nby) {
  __shared__ unsigned short As[2][8192];   // [buf][128 rows x 64 k] src-swizzled
  const int tid = threadIdx.x, w = tid >> 6, l = tid & 63, lr = l & 15, lg = l >> 4;
  const int nwg = gridDim.x;
  const int bid = (blockIdx.x & 7) * (nwg >> 3) + (blockIdx.x >> 3);
  const int bx = bid / nby, by = bid % nby;
  const int m0 = bx * 128;
  const int wr = (w >> 1) * 64, wc = (w & 1) * 64;
  const int srow = tid >> 3, sc8 = tid & 7;
  const int gcol = (sc8 ^ (srow & 7)) * 8;
  const unsigned short* Ag = A + (size_t)(m0 + srow) * lda + gcol;
  const size_t ldaa = (size_t)32 * lda;
  const unsigned short* Bg = Bp +
      ((size_t)(nOff >> 4) + by * 8 + (wc >> 4)) * 512 + lg * 128 + lr * 8;
  const size_t bks = (size_t)ldbp * 512;

  f32x4 acc[4][4] = {};
  s16x8 b0[4], b1[4];

#pragma unroll
  for (int it = 0; it < 4; ++it)
    async_copy16(&As[0][(it * 256 + tid) * 8], Ag + it * ldaa);
#pragma unroll
  for (int fj = 0; fj < 4; ++fj) {
    b0[fj] = *(const s16x8*)(Bg + fj * 512);
    b1[fj] = *(const s16x8*)(Bg + bks + fj * 512);
  }
  __syncthreads();

  int buf = 0;
  for (int kb = 0; kb < K; kb += 64) {
    int kn = (kb + 64 < K) ? kb + 64 : 0;
#pragma unroll
    for (int it = 0; it < 4; ++it)
      async_copy16(&As[buf ^ 1][(it * 256 + tid) * 8], Ag + kn + it * ldaa);
    s16x8 b0n[4];
    {
      const unsigned short* p = Bg + ((size_t)(kn >> 5)) * bks;
#pragma unroll
      for (int fj = 0; fj < 4; ++fj) b0n[fj] = *(const s16x8*)(p + fj * 512);
    }
    {
      s16x8 af[4];
#pragma unroll
      for (int fi = 0; fi < 4; ++fi) {
        int row = wr + fi * 16 + lr;
        af[fi] = *(const s16x8*)&As[buf][row * 64 + ((lg ^ (row & 7)) * 8)];
      }
#pragma unroll
      for (int fi = 0; fi < 4; ++fi)
#pragma unroll
        for (int fj = 0; fj < 4; ++fj)
          acc[fi][fj] = __builtin_amdgcn_mfma_f32_16x16x32_bf16(af[fi], b0[fj], acc[fi][fj], 0, 0, 0);
    }
    s16x8 b1n[4];
    {
      const unsigned short* p = Bg + ((size_t)((kn + 32) >> 5)) * bks;
#pragma unroll
      for (int fj = 0; fj < 4; ++fj) b1n[fj] = *(const s16x8*)(p + fj * 512);
    }
    {
      s16x8 af[4];
#pragma unroll
      for (int fi = 0; fi < 4; ++fi) {
        int row = wr + fi * 16 + lr;
        af[fi] = *(const s16x8*)&As[buf][row * 64 + (((4 + lg) ^ (row & 7)) * 8)];
      }
#pragma unroll
      for (int fi = 0; fi < 4; ++fi)
#pragma unroll
        for (int fj = 0; fj < 4; ++fj)
          acc[fi][fj] = __builtin_amdgcn_mfma_f32_16x16x32_bf16(af[fi], b1[fj], acc[fi][fj], 0, 0, 0);
    }
    __syncthreads();
#pragma unroll
    for (int fj = 0; fj < 4; ++fj) { b0[fj] = b0n[fj]; b1[fj] = b1n[fj]; }
    buf ^= 1;
  }

#pragma unroll
  for (int fj = 0; fj < 4; ++fj) {
    int colL = by * 128 + wc + fj * 16 + lr;
    float bv = bias[nOff + colL];
#pragma unroll
    for (int fi = 0; fi < 4; ++fi)
#pragma unroll
      for (int r = 0; r < 4; ++r) {
        int row = m0 + wr + fi * 16 + lg * 4 + r;
        size_t ci = (size_t)row * ldc + colL;
        float v = acc[fi][fj][r] + bv;
        if (RES) v += bf2f(resid[ci]);
        if (RELU) v = fmaxf(v, 0.f);
        if (OUTBF) ((unsigned short*)Cout)[ci] = f2bf(v);
        else ((float*)Cout)[ci] = v;
      }
  }
}

// ---------------- flash attention: BARRIER-FREE. 128 q-rows of one (h,n) --
// grid 2048: bid = qq*512 + (h + 8n); 4 waves x 2 rowtiles x 16 q-rows.
// No K LDS staging (K/V panels are 64KB -> L2-resident; staging L2-fit data
// is pure overhead). K fragments read directly from row-major k_p in the
// QK^T loop; V fragments (packed) loaded per-rt BEFORE softmax so L2 latency
// hides under the exp VALU. Pointer laundering prevents cross-rt CSE keeping
// 128 regs of K+V live. Only LDS use: wave-private P (16.9KB). Zero barriers.
__global__ __launch_bounds__(256, 2) void attn_kernel(
    const unsigned short* __restrict__ Qp, const unsigned short* __restrict__ Kp,
    const unsigned short* __restrict__ Vt, unsigned short* __restrict__ Out) {
  __shared__ unsigned short P[4][16][132];
  const int bid = blockIdx.x;
  const int qq = bid >> 9, g = bid & 511, h = g & 7, n = g >> 3;
  const int tid = threadIdx.x, w = tid >> 6, l = tid & 63, lr = l & 15, lg = l >> 4;
  const int q0 = qq * 128;

  s16x8 qf[2][2];
#pragma unroll
  for (int rt = 0; rt < 2; ++rt) {
    const size_t qb = (((size_t)(n * 512 + q0 + w * 32 + rt * 16 + lr)) * 8 + h) * 64;
    qf[rt][0] = *(const s16x8*)(Qp + qb + lg * 8);
    qf[rt][1] = *(const s16x8*)(Qp + qb + 32 + lg * 8);
  }
  const unsigned short* Vfb = Vt + ((size_t)(n * 8 + h)) * 32768 + (size_t)l * 8;
  // k_p element offset for row t, col d: (n*512+t)*512 + h*64 + d
  const unsigned short* Kb = Kp + ((size_t)(n * 512) << 9) + h * 64 + (size_t)lr * 512 + lg * 8;

  f32x4 oacc[2][4] = {};
  float m[2][4], lsum[2][4];
#pragma unroll
  for (int rt = 0; rt < 2; ++rt)
#pragma unroll
    for (int r = 0; r < 4; ++r) { m[rt][r] = -1e30f; lsum[rt][r] = 0.f; }

  for (int c = 0; c < 4; ++c) {
#pragma unroll
    for (int rt = 0; rt < 2; ++rt) {
      // launder bases so K/V loads are re-issued per rt (no cross-rt CSE)
      const unsigned short* Kc = Kb + (size_t)(c * 128) * 512;
      asm volatile("" : "+v"(Kc));
      const unsigned short* Vc = Vfb + ((size_t)(c * 16) << 9);
      asm volatile("" : "+v"(Vc));

      // QK^T: K fragments straight from L2
      f32x4 sacc[8];
      __builtin_amdgcn_s_setprio(1);
#pragma unroll
      for (int f = 0; f < 8; ++f) {
        const unsigned short* kr = Kc + (size_t)(f * 16) * 512;
        s16x8 b0 = *(const s16x8*)(kr);
        s16x8 b1 = *(const s16x8*)(kr + 32);
        f32x4 a = {};
        a = __builtin_amdgcn_mfma_f32_16x16x32_bf16(qf[rt][0], b0, a, 0, 0, 0);
        a = __builtin_amdgcn_mfma_f32_16x16x32_bf16(qf[rt][1], b1, a, 0, 0, 0);
        sacc[f] = a;
      }
      __builtin_amdgcn_s_setprio(0);

      // issue V loads now; softmax VALU below covers their L2 latency
      s16x8 vreg[16];
#pragma unroll
      for (int i = 0; i < 16; ++i)
        vreg[i] = *(const s16x8*)(Vc + ((size_t)i << 9));

      float fs[4];
#pragma unroll
      for (int r = 0; r < 4; ++r) {
        float cm = sacc[0][r];
#pragma unroll
        for (int f = 1; f < 8; ++f) cm = fmaxf(cm, sacc[f][r]);
#pragma unroll
        for (int mk = 1; mk < 16; mk <<= 1) cm = fmaxf(cm, __shfl_xor(cm, mk));
        float mn = fmaxf(m[rt][r], cm);
        fs[r] = __builtin_amdgcn_exp2f(m[rt][r] - mn);   // exp2 units
        m[rt][r] = mn;
        unsigned pa = lds_addr(&P[w][lg * 4 + r][lr]);
        float cs = 0.f;
#pragma unroll
        for (int f = 0; f < 8; ++f) {
          float p = __builtin_amdgcn_exp2f(sacc[f][r] - mn);
          asm volatile("ds_write_b16_d16_hi %0, %1 offset:%2"
                       :: "v"(pa), "v"(p), "i"(f * 32) : "memory");
          cs += p;
        }
#pragma unroll
        for (int mk = 1; mk < 16; mk <<= 1) cs += __shfl_xor(cs, mk);
        lsum[rt][r] = lsum[rt][r] * fs[r] + cs;
      }
#pragma unroll
      for (int fj = 0; fj < 4; ++fj)
#pragma unroll
        for (int r = 0; r < 4; ++r) oacc[rt][fj][r] *= fs[r];

      asm volatile("s_waitcnt lgkmcnt(0)" ::: "memory");
      __builtin_amdgcn_sched_barrier(0);
      __builtin_amdgcn_s_setprio(1);
#pragma unroll
      for (int ks = 0; ks < 4; ++ks) {
        s16x8 pa = *(const s16x8*)&P[w][lr][ks * 32 + lg * 8];
#pragma unroll
        for (int fj = 0; fj < 4; ++fj)
          oacc[rt][fj] = __builtin_amdgcn_mfma_f32_16x16x32_bf16(pa, vreg[ks * 4 + fj], oacc[rt][fj], 0, 0, 0);
      }
      __builtin_amdgcn_s_setprio(0);
    }
  }

#pragma unroll
  for (int rt = 0; rt < 2; ++rt)
#pragma unroll
    for (int fj = 0; fj < 4; ++fj)
#pragma unroll
      for (int r = 0; r < 4; ++r) {
        int qrow = q0 + w * 32 + rt * 16 + lg * 4 + r;
        Out[((size_t)(n * 512 + qrow)) * 512 + h * 64 + fj * 16 + lr] =
            f2bf(oacc[rt][fj][r] / lsum[rt][r]);
      }
}

// ---------------- layernorm: 1 wave per 512-elem row, fused residual ------
// RES: add residual R (RBF selects bf16/f32); QIN: add onehot row
template<bool XBF, bool RES, bool RBF, bool QIN, bool OUTBF>
__global__ __launch_bounds__(256) void ln_kernel(const void* __restrict__ Xv,
    const void* __restrict__ Rv, const float* __restrict__ onehot,
    const float* __restrict__ g, const float* __restrict__ bb,
    void* __restrict__ outv) {
  int row = blockIdx.x * 4 + (threadIdx.x >> 6);
  int l = threadIdx.x & 63;
  size_t base = (size_t)row * 512 + l * 8;
  float v[8];
  if (XBF) {
    s16x8 xv = *(const s16x8*)((const unsigned short*)Xv + base);
#pragma unroll
    for (int j = 0; j < 8; ++j) v[j] = bf2f((unsigned short)xv[j]);
  } else {
    const float* X = (const float*)Xv;
    float4 x0 = *(const float4*)(X + base);
    float4 x1 = *(const float4*)(X + base + 4);
    v[0] = x0.x; v[1] = x0.y; v[2] = x0.z; v[3] = x0.w;
    v[4] = x1.x; v[5] = x1.y; v[6] = x1.z; v[7] = x1.w;
  }
  if (RES) {
    if (RBF) {
      s16x8 rv = *(const s16x8*)((const unsigned short*)Rv + base);
#pragma unroll
      for (int j = 0; j < 8; ++j) v[j] += bf2f((unsigned short)rv[j]);
    } else {
      const float* R = (const float*)Rv;
      float4 r0 = *(const float4*)(R + base);
      float4 r1 = *(const float4*)(R + base + 4);
      v[0] += r0.x; v[1] += r0.y; v[2] += r0.z; v[3] += r0.w;
      v[4] += r1.x; v[5] += r1.y; v[6] += r1.z; v[7] += r1.w;
    }
  }
  if (QIN) {
    size_t ob = (size_t)(row & 511) * 512 + l * 8;
    float4 o0 = *(const float4*)(onehot + ob);
    float4 o1 = *(const float4*)(onehot + ob + 4);
    v[0] += o0.x; v[1] += o0.y; v[2] += o0.z; v[3] += o0.w;
    v[4] += o1.x; v[5] += o1.y; v[6] += o1.z; v[7] += o1.w;
  }
  float s = 0.f, ss = 0.f;
#pragma unroll
  for (int j = 0; j < 8; ++j) { s += v[j]; ss += v[j] * v[j]; }
#pragma unroll
  for (int mk = 1; mk < 64; mk <<= 1) { s += __shfl_xor(s, mk); ss += __shfl_xor(ss, mk); }
  float mu = s * (1.f / 512.f);
  float inv = rsqrtf(ss * (1.f / 512.f) - mu * mu + 1e-5f);
#pragma unroll
  for (int j = 0; j < 8; ++j) {
    int e = l * 8 + j;
    float y = (v[j] - mu) * inv * g[e] + bb[e];
    if (OUTBF) ((unsigned short*)outv)[base + j] = f2bf(y);
    else ((float*)outv)[base + j] = y;
  }
}

extern "C" void kernel_launch(void* const* d_in, const int* in_sizes, int n_in,
                              void* d_out, int out_size, void* d_ws, size_t ws_size,
                              hipStream_t stream) {
  const float* value  = (const float*)d_in[0];
  const float* key_in = (const float*)d_in[1];
  const float* query  = (const float*)d_in[2];
  const int*   pi     = (const int*)d_in[3];
  const float* I_mat  = (const float*)d_in[4];
  const float* ohW    = (const float*)d_in[5];
  const float* ohb    = (const float*)d_in[6];
  const float* Wv     = (const float*)d_in[7];
  const float* Wk     = (const float*)d_in[8];
  const float* Wq     = (const float*)d_in[9];
  const float* Wo     = (const float*)d_in[10];
  const float* bo     = (const float*)d_in[11];
  const float* g1     = (const float*)d_in[12];
  const float* b1     = (const float*)d_in[13];
  const float* g2     = (const float*)d_in[14];
  const float* b2     = (const float*)d_in[15];
  const float* W1     = (const float*)d_in[16];
  const float* bf1    = (const float*)d_in[17];
  const float* W2     = (const float*)d_in[18];
  const float* bf2    = (const float*)d_in[19];

  char* ws = (char*)d_ws;
  const size_t MB = 1024 * 1024;
  unsigned short* q_p  = (unsigned short*)d_out;      // d_out as scratch
  unsigned short* k_p  = q_p + 16777216;
  unsigned short* vP     = (unsigned short*)(ws + 0);        // 32MB, fragment-packed
  unsigned short* attn_o = (unsigned short*)(ws + 32 * MB);  // 32MB
  unsigned short* x_b    = (unsigned short*)(ws + 64 * MB);  // 32MB
  unsigned short* ff1h   = (unsigned short*)(ws + 0);        // 64MB half (aliases vP/attn_o)
  float*          onehot = (float*)(ws + 96 * MB);           // 1MB
  unsigned short* Wv_b   = (unsigned short*)(ws + 97 * MB);
  unsigned short* Wk_b   = Wv_b + 4096;
  unsigned short* Wq_b   = Wk_b + 4096;
  unsigned short* Wop    = Wq_b + 4096;      // 512KB packed
  unsigned short* W1p    = Wop + 262144;     // 2MB packed
  unsigned short* W2p    = W1p + 1048576;    // 2MB packed

  prep_kernel<<<1667, 256, 0, stream>>>(pi, I_mat, ohW, ohb, onehot,
      Wv, Wk, Wq, Wv_b, Wk_b, Wq_b, Wo, W1, W2, Wop, W1p, W2p);

  proj_all<<<12288, 256, 0, stream>>>(value, key_in, query,
      Wv_b, Wk_b, Wq_b, onehot, vP, k_p, q_p);

  attn_kernel<<<2048, 256, 0, stream>>>(q_p, k_p, vP, attn_o);

  // Wo: x_b(bf16) = attn_o @ Wo + bo
  gemmF<false, true, false><<<1024, 256, 0, stream>>>(
      attn_o, 512, Wop, 32, 0, bo, x_b, nullptr, 512, 32768, 512, 4);
  // LN1 in place on x_b, residual = query + onehot
  ln_kernel<true, true, false, true, true><<<8192, 256, 0, stream>>>(
      x_b, query, onehot, g1, b1, x_b);

  // FFN split over 2 row-halves (M=16384 each); FFN2 fuses +x residual
  for (int hf = 0; hf < 2; ++hf) {
    const unsigned short* xh = x_b + (size_t)hf * 16384 * 512;
    gemmF<true, true, false><<<2048, 256, 0, stream>>>(
        xh, 512, W1p, 128, 0, bf1, ff1h, nullptr, 2048, 16384, 512, 16);
    gemmF<false, false, true><<<512, 256, 0, stream>>>(
        ff1h, 2048, W2p, 32, 0, bf2, (float*)d_out + (size_t)hf * 16384 * 512,
        xh, 512, 16384, 2048, 4);
  }
  // LN2: X = d_out f32 (residual already added) -> d_out in place
  ln_kernel<false, false, false, false, false><<<8192, 256, 0, stream>>>(
      d_out, nullptr, nullptr, g2, b2, d_out);
}

// Round 16
// 438.027 us; speedup vs baseline: 1.1292x; 1.1292x over previous
//
#include <hip/hip_runtime.h>

typedef __attribute__((ext_vector_type(8))) short s16x8;
typedef __attribute__((ext_vector_type(4))) float f32x4;

#define TN 288

__device__ __forceinline__ unsigned short f2bf(float f) {
  union { float f; unsigned u; } v; v.f = f;
  unsigned r = v.u + 0x7fffu + ((v.u >> 16) & 1u);
  return (unsigned short)(r >> 16);
}
__device__ __forceinline__ float bf2f(unsigned short u) {
  union { float f; unsigned u; } v; v.u = ((unsigned)u) << 16;
  return v.f;
}
__device__ __forceinline__ unsigned lds_addr(const void* p) {
  return (unsigned)(unsigned long long)(const __attribute__((address_space(3))) char*)p;
}
__device__ __forceinline__ void async_copy16(unsigned short* lds, const unsigned short* g) {
  __builtin_amdgcn_global_load_lds(
      (const __attribute__((address_space(1))) unsigned int*)g,
      (__attribute__((address_space(3))) unsigned int*)lds, 16, 0, 0);
}

// ---------------- fused prep: onehot + weight casts + packs (1 launch) ----
__device__ __forceinline__ void pack_body(const float* __restrict__ W,
    unsigned short* __restrict__ out, int N, long t) {
  int lr = (int)(t & 15);
  int lg = (int)((t >> 4) & 3);
  long g6 = t >> 6;
  int nt = N >> 4;
  int n16 = (int)(g6 % nt);
  int kb = (int)(g6 / nt) << 5;
  int k = kb + lg * 8;
  int col = n16 * 16 + lr;
  s16x8 v;
#pragma unroll
  for (int j = 0; j < 8; ++j) v[j] = (short)f2bf(W[(size_t)(k + j) * N + col]);
  *(s16x8*)(out + t * 8) = v;
}

__global__ __launch_bounds__(256) void prep_kernel(const int* __restrict__ pi,
    const float* __restrict__ I_mat, const float* __restrict__ ohW,
    const float* __restrict__ ohb, float* __restrict__ onehot,
    const float* __restrict__ Wv, const float* __restrict__ Wk,
    const float* __restrict__ Wq, unsigned short* __restrict__ Wv_b,
    unsigned short* __restrict__ Wk_b, unsigned short* __restrict__ Wq_b,
    const float* __restrict__ Wo, const float* __restrict__ W1,
    const float* __restrict__ W2, unsigned short* __restrict__ Wop,
    unsigned short* __restrict__ W1p, unsigned short* __restrict__ W2p) {
  int b = blockIdx.x, tid = threadIdx.x;
  if (b < 512) {
    int t = b;
    int r = (pi[0] + t) % TN;
    float acc0 = ohb[tid], acc1 = ohb[tid + 256];
    const float* Ir = I_mat + (size_t)r * TN;
    for (int j = 0; j < TN; ++j) {
      float iv = Ir[j];
      acc0 += iv * ohW[(size_t)j * 512 + tid];
      acc1 += iv * ohW[(size_t)j * 512 + tid + 256];
    }
    onehot[(size_t)t * 512 + tid] = acc0;
    onehot[(size_t)t * 512 + tid + 256] = acc1;
  } else if (b < 640) {
    pack_body(Wo, Wop, 512, (long)(b - 512) * 256 + tid);
  } else if (b < 1152) {
    pack_body(W1, W1p, 2048, (long)(b - 640) * 256 + tid);
  } else if (b < 1664) {
    pack_body(W2, W2p, 512, (long)(b - 1152) * 256 + tid);
  } else {
    int which = b - 1664;
    const float* src = which == 0 ? Wv : (which == 1 ? Wk : Wq);
    unsigned short* dst = which == 0 ? Wv_b : (which == 1 ? Wk_b : Wq_b);
    float sc = which == 2 ? 0.06375871424f : 1.f;  // Wq: 1/sqrt(512)*log2(e)
#pragma unroll
    for (int j = 0; j < 4; ++j) {
      int i = tid * 16 + j * 4;
      float4 f = *(const float4*)(src + i);
      unsigned lo = (unsigned)f2bf(f.x * sc) | ((unsigned)f2bf(f.y * sc) << 16);
      unsigned hi = (unsigned)f2bf(f.z * sc) | ((unsigned)f2bf(f.w * sc) << 16);
      *(uint2*)(dst + i) = make_uint2(lo, hi);
    }
  }
}

// ---------------- fused projection GEMMs: grid 12288, which = bid>>12 -----
// which 0: V packed into MFMA-fragment order:
//   vP[(n*8+h)*32768 + ((c*16 + ks*4 + fj)*64 + l)*8 + j] =
//     V[t = c*128+ks*32+(l>>4)*8+j][d = fj*16+(l&15)]   (per (n,h))
// which 1: K row-major; which 2: Q (+onehot), row-major
__global__ __launch_bounds__(256) void proj_all(
    const float* __restrict__ value, const float* __restrict__ key_in,
    const float* __restrict__ query, const unsigned short* __restrict__ Wv_b,
    const unsigned short* __restrict__ Wk_b, const unsigned short* __restrict__ Wq_b,
    const float* __restrict__ onehot, unsigned short* __restrict__ vP,
    unsigned short* __restrict__ k_p, unsigned short* __restrict__ q_p) {
  __shared__ unsigned short As[64][40];
  __shared__ unsigned short Bs[64][40];   // Bs[col][k]
  __shared__ unsigned short Cs[64][72];   // V-pack bounce
  const int which = blockIdx.x >> 12;
  const int mb = blockIdx.x & 4095;
  const float* A = which == 0 ? value : (which == 1 ? key_in : query);
  const unsigned short* B = which == 0 ? Wv_b : (which == 1 ? Wk_b : Wq_b);
  unsigned short* C = which == 0 ? vP : (which == 1 ? k_p : q_p);
  const bool qin = (which == 2);
  const int m0 = mb * 64;
  const int tid = threadIdx.x, w = tid >> 6, l = tid & 63, lr = l & 15, lg = l >> 4;
  const int wr = (w >> 1) * 32, wc = (w & 1) * 32;
  const int aRow = (tid * 8) >> 5, aK = (tid * 8) & 31;
  const int bK = (tid * 8) >> 6, bCol = (tid * 8) & 63;
  f32x4 acc[2][2] = {};
  for (int kb = 0; kb < 64; kb += 32) {
    size_t fl = (size_t)(m0 + aRow) * 64 + kb + aK;
    float4 f0 = *(const float4*)(A + fl);
    float4 f1 = *(const float4*)(A + fl + 4);
    if (qin) {
      const float* oh = onehot + (fl & 262143);
      float4 o0 = *(const float4*)(oh);
      float4 o1 = *(const float4*)(oh + 4);
      f0.x += o0.x; f0.y += o0.y; f0.z += o0.z; f0.w += o0.w;
      f1.x += o1.x; f1.y += o1.y; f1.z += o1.z; f1.w += o1.w;
    }
    s16x8 av;
    av[0] = (short)f2bf(f0.x); av[1] = (short)f2bf(f0.y);
    av[2] = (short)f2bf(f0.z); av[3] = (short)f2bf(f0.w);
    av[4] = (short)f2bf(f1.x); av[5] = (short)f2bf(f1.y);
    av[6] = (short)f2bf(f1.z); av[7] = (short)f2bf(f1.w);
    *(s16x8*)&As[aRow][aK] = av;
    s16x8 bv = *(const s16x8*)(B + (size_t)(kb + bK) * 64 + bCol);
#pragma unroll
    for (int j = 0; j < 8; ++j) Bs[bCol + j][bK] = (unsigned short)bv[j];
    __syncthreads();
    s16x8 af0 = *(const s16x8*)&As[wr + lr][lg * 8];
    s16x8 af1 = *(const s16x8*)&As[wr + 16 + lr][lg * 8];
    s16x8 bf0 = *(const s16x8*)&Bs[wc + lr][lg * 8];
    s16x8 bf1 = *(const s16x8*)&Bs[wc + 16 + lr][lg * 8];
    acc[0][0] = __builtin_amdgcn_mfma_f32_16x16x32_bf16(af0, bf0, acc[0][0], 0, 0, 0);
    acc[0][1] = __builtin_amdgcn_mfma_f32_16x16x32_bf16(af0, bf1, acc[0][1], 0, 0, 0);
    acc[1][0] = __builtin_amdgcn_mfma_f32_16x16x32_bf16(af1, bf0, acc[1][0], 0, 0, 0);
    acc[1][1] = __builtin_amdgcn_mfma_f32_16x16x32_bf16(af1, bf1, acc[1][1], 0, 0, 0);
    __syncthreads();
  }
  if (which != 0) {
#pragma unroll
    for (int fi = 0; fi < 2; ++fi)
#pragma unroll
      for (int fj = 0; fj < 2; ++fj)
#pragma unroll
        for (int r = 0; r < 4; ++r) {
          int row = m0 + wr + fi * 16 + lg * 4 + r;
          int col = wc + fj * 16 + lr;
          C[(size_t)row * 64 + col] = f2bf(acc[fi][fj][r]);
        }
  } else {
#pragma unroll
    for (int fi = 0; fi < 2; ++fi)
#pragma unroll
      for (int fj = 0; fj < 2; ++fj)
#pragma unroll
        for (int r = 0; r < 4; ++r)
          Cs[wr + fi * 16 + lg * 4 + r][wc + fj * 16 + lr] = f2bf(acc[fi][fj][r]);
    __syncthreads();
    // rows m0..m0+63 encode (n*512+t)*8+h: t = t0 + r_local/8, h = r_local&7
    int nIdx = m0 >> 12, t0 = (m0 >> 3) & 511;
    int cc = t0 >> 7, ksv = (t0 >> 5) & 3, lgv = (t0 >> 3) & 3;
#pragma unroll
    for (int it = 0; it < 2; ++it) {
      int p = tid + it * 256;
      int hh = p >> 6, d = p & 63;
      s16x8 vv;
#pragma unroll
      for (int j = 0; j < 8; ++j) vv[j] = (short)Cs[j * 8 + hh][d];
      size_t dst = ((size_t)(nIdx * 8 + hh)) * 32768 +
                   (size_t)(((cc * 16 + ksv * 4 + (d >> 4)) * 64) + lgv * 16 + (d & 15)) * 8;
      *(s16x8*)(C + dst) = vv;
    }
  }
}

// ---------------- big GEMM: BK=64, XCD-swizzled 1D grid, B 2-deep prefetch
// RES: add bf16 residual (same ldc) in epilogue
template<bool RELU, bool OUTBF, bool RES>
__global__ __launch_bounds__(256) void gemmF(
    const unsigned short* __restrict__ A, int lda,
    const unsigned short* __restrict__ Bp, int ldbp, int nOff,
    const float* __restrict__ bias, void* __restrict__ Cout,
    const unsigned short* __restrict__ resid, int ldc,
    int M, int K, int nby) {
  __shared__ unsigned short As[2][8192];   // [buf][128 rows x 64 k] src-swizzled
  const int tid = threadIdx.x, w = tid >> 6, l = tid & 63, lr = l & 15, lg = l >> 4;
  const int nwg = gridDim.x;
  const int bid = (blockIdx.x & 7) * (nwg >> 3) + (blockIdx.x >> 3);
  const int bx = bid / nby, by = bid % nby;
  const int m0 = bx * 128;
  const int wr = (w >> 1) * 64, wc = (w & 1) * 64;
  const int srow = tid >> 3, sc8 = tid & 7;
  const int gcol = (sc8 ^ (srow & 7)) * 8;
  const unsigned short* Ag = A + (size_t)(m0 + srow) * lda + gcol;
  const size_t ldaa = (size_t)32 * lda;
  const unsigned short* Bg = Bp +
      ((size_t)(nOff >> 4) + by * 8 + (wc >> 4)) * 512 + lg * 128 + lr * 8;
  const size_t bks = (size_t)ldbp * 512;

  f32x4 acc[4][4] = {};
  s16x8 b0[4], b1[4];

#pragma unroll
  for (int it = 0; it < 4; ++it)
    async_copy16(&As[0][(it * 256 + tid) * 8], Ag + it * ldaa);
#pragma unroll
  for (int fj = 0; fj < 4; ++fj) {
    b0[fj] = *(const s16x8*)(Bg + fj * 512);
    b1[fj] = *(const s16x8*)(Bg + bks + fj * 512);
  }
  __syncthreads();

  int buf = 0;
  for (int kb = 0; kb < K; kb += 64) {
    int kn = (kb + 64 < K) ? kb + 64 : 0;
#pragma unroll
    for (int it = 0; it < 4; ++it)
      async_copy16(&As[buf ^ 1][(it * 256 + tid) * 8], Ag + kn + it * ldaa);
    s16x8 b0n[4];
    {
      const unsigned short* p = Bg + ((size_t)(kn >> 5)) * bks;
#pragma unroll
      for (int fj = 0; fj < 4; ++fj) b0n[fj] = *(const s16x8*)(p + fj * 512);
    }
    {
      s16x8 af[4];
#pragma unroll
      for (int fi = 0; fi < 4; ++fi) {
        int row = wr + fi * 16 + lr;
        af[fi] = *(const s16x8*)&As[buf][row * 64 + ((lg ^ (row & 7)) * 8)];
      }
#pragma unroll
      for (int fi = 0; fi < 4; ++fi)
#pragma unroll
        for (int fj = 0; fj < 4; ++fj)
          acc[fi][fj] = __builtin_amdgcn_mfma_f32_16x16x32_bf16(af[fi], b0[fj], acc[fi][fj], 0, 0, 0);
    }
    s16x8 b1n[4];
    {
      const unsigned short* p = Bg + ((size_t)((kn + 32) >> 5)) * bks;
#pragma unroll
      for (int fj = 0; fj < 4; ++fj) b1n[fj] = *(const s16x8*)(p + fj * 512);
    }
    {
      s16x8 af[4];
#pragma unroll
      for (int fi = 0; fi < 4; ++fi) {
        int row = wr + fi * 16 + lr;
        af[fi] = *(const s16x8*)&As[buf][row * 64 + (((4 + lg) ^ (row & 7)) * 8)];
      }
#pragma unroll
      for (int fi = 0; fi < 4; ++fi)
#pragma unroll
        for (int fj = 0; fj < 4; ++fj)
          acc[fi][fj] = __builtin_amdgcn_mfma_f32_16x16x32_bf16(af[fi], b1[fj], acc[fi][fj], 0, 0, 0);
    }
    __syncthreads();
#pragma unroll
    for (int fj = 0; fj < 4; ++fj) { b0[fj] = b0n[fj]; b1[fj] = b1n[fj]; }
    buf ^= 1;
  }

#pragma unroll
  for (int fj = 0; fj < 4; ++fj) {
    int colL = by * 128 + wc + fj * 16 + lr;
    float bv = bias[nOff + colL];
#pragma unroll
    for (int fi = 0; fi < 4; ++fi)
#pragma unroll
      for (int r = 0; r < 4; ++r) {
        int row = m0 + wr + fi * 16 + lg * 4 + r;
        size_t ci = (size_t)row * ldc + colL;
        float v = acc[fi][fj][r] + bv;
        if (RES) v += bf2f(resid[ci]);
        if (RELU) v = fmaxf(v, 0.f);
        if (OUTBF) ((unsigned short*)Cout)[ci] = f2bf(v);
        else ((float*)Cout)[ci] = v;
      }
  }
}

// ---------------- flash attention (R14, measured best): 128 q-rows/(h,n) --
// grid 2048: bid = qq*512 + (h + 8n); 4 waves x 2 rowtiles x 16 q-rows.
// Q in regs; K staged in LDS per chunk (cooperative vector loads — the LDS
// stage provides inter-wave K reuse; R15 proved removing it costs 1.6x);
// V fragment-packed in global, all 16 fragments hoisted into vreg at chunk
// top so L2 latency hides under QK^T + softmax; exp2-unit softmax.
__global__ __launch_bounds__(256, 2) void attn_kernel(
    const unsigned short* __restrict__ Qp, const unsigned short* __restrict__ Kp,
    const unsigned short* __restrict__ Vt, unsigned short* __restrict__ Out) {
  __shared__ unsigned short KS[128][72];
  __shared__ unsigned short P[4][16][132];
  const int bid = blockIdx.x;
  const int qq = bid >> 9, g = bid & 511, h = g & 7, n = g >> 3;
  const int tid = threadIdx.x, w = tid >> 6, l = tid & 63, lr = l & 15, lg = l >> 4;
  const int q0 = qq * 128;

  s16x8 qf[2][2];
#pragma unroll
  for (int rt = 0; rt < 2; ++rt) {
    const size_t qb = (((size_t)(n * 512 + q0 + w * 32 + rt * 16 + lr)) * 8 + h) * 64;
    qf[rt][0] = *(const s16x8*)(Qp + qb + lg * 8);
    qf[rt][1] = *(const s16x8*)(Qp + qb + 32 + lg * 8);
  }
  const unsigned short* Vfb = Vt + ((size_t)(n * 8 + h)) * 32768 + (size_t)l * 8;

  f32x4 oacc[2][4] = {};
  float m[2][4], lsum[2][4];
#pragma unroll
  for (int rt = 0; rt < 2; ++rt)
#pragma unroll
    for (int r = 0; r < 4; ++r) { m[rt][r] = -1e30f; lsum[rt][r] = 0.f; }
  s16x8 vreg[16];

  // prologue: stage K(0), hoist V(0)
#pragma unroll
  for (int it = 0; it < 4; ++it) {
    int idx = tid + it * 256;
    int rr = idx >> 3, dd = (idx & 7) * 8;
    *(s16x8*)&KS[rr][dd] =
        *(const s16x8*)(Kp + (((size_t)(n * 512 + rr)) * 8 + h) * 64 + dd);
  }
#pragma unroll
  for (int i = 0; i < 16; ++i)
    vreg[i] = *(const s16x8*)(Vfb + ((size_t)i << 9));
  __syncthreads();

  for (int c = 0; c < 4; ++c) {
    if (c) {
      __syncthreads();
#pragma unroll
      for (int it = 0; it < 4; ++it) {
        int idx = tid + it * 256;
        int rr = idx >> 3, dd = (idx & 7) * 8;
        *(s16x8*)&KS[rr][dd] =
            *(const s16x8*)(Kp + (((size_t)(n * 512 + c * 128 + rr)) * 8 + h) * 64 + dd);
      }
#pragma unroll
      for (int i = 0; i < 16; ++i)
        vreg[i] = *(const s16x8*)(Vfb + ((size_t)(c * 16 + i) << 9));
      __syncthreads();
    }
#pragma unroll
    for (int rt = 0; rt < 2; ++rt) {
      f32x4 sacc[8];
      __builtin_amdgcn_s_setprio(1);
#pragma unroll
      for (int f = 0; f < 8; ++f) {
        s16x8 b0 = *(const s16x8*)&KS[f * 16 + lr][lg * 8];
        s16x8 b1 = *(const s16x8*)&KS[f * 16 + lr][32 + lg * 8];
        f32x4 a = {};
        a = __builtin_amdgcn_mfma_f32_16x16x32_bf16(qf[rt][0], b0, a, 0, 0, 0);
        a = __builtin_amdgcn_mfma_f32_16x16x32_bf16(qf[rt][1], b1, a, 0, 0, 0);
        sacc[f] = a;
      }
      __builtin_amdgcn_s_setprio(0);

      float fs[4];
#pragma unroll
      for (int r = 0; r < 4; ++r) {
        float cm = sacc[0][r];
#pragma unroll
        for (int f = 1; f < 8; ++f) cm = fmaxf(cm, sacc[f][r]);
#pragma unroll
        for (int mk = 1; mk < 16; mk <<= 1) cm = fmaxf(cm, __shfl_xor(cm, mk));
        float mn = fmaxf(m[rt][r], cm);
        fs[r] = __builtin_amdgcn_exp2f(m[rt][r] - mn);   // exp2 units
        m[rt][r] = mn;
        unsigned pa = lds_addr(&P[w][lg * 4 + r][lr]);
        float cs = 0.f;
#pragma unroll
        for (int f = 0; f < 8; ++f) {
          float p = __builtin_amdgcn_exp2f(sacc[f][r] - mn);
          asm volatile("ds_write_b16_d16_hi %0, %1 offset:%2"
                       :: "v"(pa), "v"(p), "i"(f * 32) : "memory");
          cs += p;
        }
#pragma unroll
        for (int mk = 1; mk < 16; mk <<= 1) cs += __shfl_xor(cs, mk);
        lsum[rt][r] = lsum[rt][r] * fs[r] + cs;
      }
#pragma unroll
      for (int fj = 0; fj < 4; ++fj)
#pragma unroll
        for (int r = 0; r < 4; ++r) oacc[rt][fj][r] *= fs[r];

      asm volatile("s_waitcnt lgkmcnt(0)" ::: "memory");
      __builtin_amdgcn_sched_barrier(0);
      __builtin_amdgcn_s_setprio(1);
#pragma unroll
      for (int ks = 0; ks < 4; ++ks) {
        s16x8 pa = *(const s16x8*)&P[w][lr][ks * 32 + lg * 8];
#pragma unroll
        for (int fj = 0; fj < 4; ++fj)
          oacc[rt][fj] = __builtin_amdgcn_mfma_f32_16x16x32_bf16(pa, vreg[ks * 4 + fj], oacc[rt][fj], 0, 0, 0);
      }
      __builtin_amdgcn_s_setprio(0);
    }
  }

#pragma unroll
  for (int rt = 0; rt < 2; ++rt)
#pragma unroll
    for (int fj = 0; fj < 4; ++fj)
#pragma unroll
      for (int r = 0; r < 4; ++r) {
        int qrow = q0 + w * 32 + rt * 16 + lg * 4 + r;
        Out[((size_t)(n * 512 + qrow)) * 512 + h * 64 + fj * 16 + lr] =
            f2bf(oacc[rt][fj][r] / lsum[rt][r]);
      }
}

// ---------------- layernorm: 1 wave per 512-elem row, fused residual ------
// RES: add residual R (RBF selects bf16/f32); QIN: add onehot row
template<bool XBF, bool RES, bool RBF, bool QIN, bool OUTBF>
__global__ __launch_bounds__(256) void ln_kernel(const void* __restrict__ Xv,
    const void* __restrict__ Rv, const float* __restrict__ onehot,
    const float* __restrict__ g, const float* __restrict__ bb,
    void* __restrict__ outv) {
  int row = blockIdx.x * 4 + (threadIdx.x >> 6);
  int l = threadIdx.x & 63;
  size_t base = (size_t)row * 512 + l * 8;
  float v[8];
  if (XBF) {
    s16x8 xv = *(const s16x8*)((const unsigned short*)Xv + base);
#pragma unroll
    for (int j = 0; j < 8; ++j) v[j] = bf2f((unsigned short)xv[j]);
  } else {
    const float* X = (const float*)Xv;
    float4 x0 = *(const float4*)(X + base);
    float4 x1 = *(const float4*)(X + base + 4);
    v[0] = x0.x; v[1] = x0.y; v[2] = x0.z; v[3] = x0.w;
    v[4] = x1.x; v[5] = x1.y; v[6] = x1.z; v[7] = x1.w;
  }
  if (RES) {
    if (RBF) {
      s16x8 rv = *(const s16x8*)((const unsigned short*)Rv + base);
#pragma unroll
      for (int j = 0; j < 8; ++j) v[j] += bf2f((unsigned short)rv[j]);
    } else {
      const float* R = (const float*)Rv;
      float4 r0 = *(const float4*)(R + base);
      float4 r1 = *(const float4*)(R + base + 4);
      v[0] += r0.x; v[1] += r0.y; v[2] += r0.z; v[3] += r0.w;
      v[4] += r1.x; v[5] += r1.y; v[6] += r1.z; v[7] += r1.w;
    }
  }
  if (QIN) {
    size_t ob = (size_t)(row & 511) * 512 + l * 8;
    float4 o0 = *(const float4*)(onehot + ob);
    float4 o1 = *(const float4*)(onehot + ob + 4);
    v[0] += o0.x; v[1] += o0.y; v[2] += o0.z; v[3] += o0.w;
    v[4] += o1.x; v[5] += o1.y; v[6] += o1.z; v[7] += o1.w;
  }
  float s = 0.f, ss = 0.f;
#pragma unroll
  for (int j = 0; j < 8; ++j) { s += v[j]; ss += v[j] * v[j]; }
#pragma unroll
  for (int mk = 1; mk < 64; mk <<= 1) { s += __shfl_xor(s, mk); ss += __shfl_xor(ss, mk); }
  float mu = s * (1.f / 512.f);
  float inv = rsqrtf(ss * (1.f / 512.f) - mu * mu + 1e-5f);
#pragma unroll
  for (int j = 0; j < 8; ++j) {
    int e = l * 8 + j;
    float y = (v[j] - mu) * inv * g[e] + bb[e];
    if (OUTBF) ((unsigned short*)outv)[base + j] = f2bf(y);
    else ((float*)outv)[base + j] = y;
  }
}

extern "C" void kernel_launch(void* const* d_in, const int* in_sizes, int n_in,
                              void* d_out, int out_size, void* d_ws, size_t ws_size,
                              hipStream_t stream) {
  const float* value  = (const float*)d_in[0];
  const float* key_in = (const float*)d_in[1];
  const float* query  = (const float*)d_in[2];
  const int*   pi     = (const int*)d_in[3];
  const float* I_mat  = (const float*)d_in[4];
  const float* ohW    = (const float*)d_in[5];
  const float* ohb    = (const float*)d_in[6];
  const float* Wv     = (const float*)d_in[7];
  const float* Wk     = (const float*)d_in[8];
  const float* Wq     = (const float*)d_in[9];
  const float* Wo     = (const float*)d_in[10];
  const float* bo     = (const float*)d_in[11];
  const float* g1     = (const float*)d_in[12];
  const float* b1     = (const float*)d_in[13];
  const float* g2     = (const float*)d_in[14];
  const float* b2     = (const float*)d_in[15];
  const float* W1     = (const float*)d_in[16];
  const float* bf1    = (const float*)d_in[17];
  const float* W2     = (const float*)d_in[18];
  const float* bf2    = (const float*)d_in[19];

  char* ws = (char*)d_ws;
  const size_t MB = 1024 * 1024;
  unsigned short* q_p  = (unsigned short*)d_out;      // d_out as scratch
  unsigned short* k_p  = q_p + 16777216;
  unsigned short* vP     = (unsigned short*)(ws + 0);        // 32MB, fragment-packed
  unsigned short* attn_o = (unsigned short*)(ws + 32 * MB);  // 32MB
  unsigned short* x_b    = (unsigned short*)(ws + 64 * MB);  // 32MB
  unsigned short* ff1h   = (unsigned short*)(ws + 0);        // 64MB half (aliases vP/attn_o)
  float*          onehot = (float*)(ws + 96 * MB);           // 1MB
  unsigned short* Wv_b   = (unsigned short*)(ws + 97 * MB);
  unsigned short* Wk_b   = Wv_b + 4096;
  unsigned short* Wq_b   = Wk_b + 4096;
  unsigned short* Wop    = Wq_b + 4096;      // 512KB packed
  unsigned short* W1p    = Wop + 262144;     // 2MB packed
  unsigned short* W2p    = W1p + 1048576;    // 2MB packed

  prep_kernel<<<1667, 256, 0, stream>>>(pi, I_mat, ohW, ohb, onehot,
      Wv, Wk, Wq, Wv_b, Wk_b, Wq_b, Wo, W1, W2, Wop, W1p, W2p);

  proj_all<<<12288, 256, 0, stream>>>(value, key_in, query,
      Wv_b, Wk_b, Wq_b, onehot, vP, k_p, q_p);

  attn_kernel<<<2048, 256, 0, stream>>>(q_p, k_p, vP, attn_o);

  // Wo: x_b(bf16) = attn_o @ Wo + bo
  gemmF<false, true, false><<<1024, 256, 0, stream>>>(
      attn_o, 512, Wop, 32, 0, bo, x_b, nullptr, 512, 32768, 512, 4);
  // LN1 in place on x_b, residual = query + onehot
  ln_kernel<true, true, false, true, true><<<8192, 256, 0, stream>>>(
      x_b, query, onehot, g1, b1, x_b);

  // FFN split over 2 row-halves (M=16384 each); FFN2 fuses +x residual
  for (int hf = 0; hf < 2; ++hf) {
    const unsigned short* xh = x_b + (size_t)hf * 16384 * 512;
    gemmF<true, true, false><<<2048, 256, 0, stream>>>(
        xh, 512, W1p, 128, 0, bf1, ff1h, nullptr, 2048, 16384, 512, 16);
    gemmF<false, false, true><<<512, 256, 0, stream>>>(
        ff1h, 2048, W2p, 32, 0, bf2, (float*)d_out + (size_t)hf * 16384 * 512,
        xh, 512, 16384, 2048, 4);
  }
  // LN2: X = d_out f32 (residual already added) -> d_out in place
  ln_kernel<false, false, false, false, false><<<8192, 256, 0, stream>>>(
      d_out, nullptr, nullptr, g2, b2, d_out);
}

// Round 17
// 433.113 us; speedup vs baseline: 1.1420x; 1.0113x over previous
//
#include <hip/hip_runtime.h>

typedef __attribute__((ext_vector_type(8))) short s16x8;
typedef __attribute__((ext_vector_type(4))) float f32x4;

#define TN 288

__device__ __forceinline__ unsigned short f2bf(float f) {
  union { float f; unsigned u; } v; v.f = f;
  unsigned r = v.u + 0x7fffu + ((v.u >> 16) & 1u);
  return (unsigned short)(r >> 16);
}
__device__ __forceinline__ float bf2f(unsigned short u) {
  union { float f; unsigned u; } v; v.u = ((unsigned)u) << 16;
  return v.f;
}
__device__ __forceinline__ unsigned lds_addr(const void* p) {
  return (unsigned)(unsigned long long)(const __attribute__((address_space(3))) char*)p;
}
__device__ __forceinline__ void async_copy16(unsigned short* lds, const unsigned short* g) {
  __builtin_amdgcn_global_load_lds(
      (const __attribute__((address_space(1))) unsigned int*)g,
      (__attribute__((address_space(3))) unsigned int*)lds, 16, 0, 0);
}

// ---------------- fused prep: onehot + weight casts + packs (1 launch) ----
__device__ __forceinline__ void pack_body(const float* __restrict__ W,
    unsigned short* __restrict__ out, int N, long t) {
  int lr = (int)(t & 15);
  int lg = (int)((t >> 4) & 3);
  long g6 = t >> 6;
  int nt = N >> 4;
  int n16 = (int)(g6 % nt);
  int kb = (int)(g6 / nt) << 5;
  int k = kb + lg * 8;
  int col = n16 * 16 + lr;
  s16x8 v;
#pragma unroll
  for (int j = 0; j < 8; ++j) v[j] = (short)f2bf(W[(size_t)(k + j) * N + col]);
  *(s16x8*)(out + t * 8) = v;
}

__global__ __launch_bounds__(256) void prep_kernel(const int* __restrict__ pi,
    const float* __restrict__ I_mat, const float* __restrict__ ohW,
    const float* __restrict__ ohb, float* __restrict__ onehot,
    const float* __restrict__ Wv, const float* __restrict__ Wk,
    const float* __restrict__ Wq, unsigned short* __restrict__ Wv_b,
    unsigned short* __restrict__ Wk_b, unsigned short* __restrict__ Wq_b,
    const float* __restrict__ Wo, const float* __restrict__ W1,
    const float* __restrict__ W2, unsigned short* __restrict__ Wop,
    unsigned short* __restrict__ W1p, unsigned short* __restrict__ W2p) {
  int b = blockIdx.x, tid = threadIdx.x;
  if (b < 512) {
    int t = b;
    int r = (pi[0] + t) % TN;
    float acc0 = ohb[tid], acc1 = ohb[tid + 256];
    const float* Ir = I_mat + (size_t)r * TN;
    for (int j = 0; j < TN; ++j) {
      float iv = Ir[j];
      acc0 += iv * ohW[(size_t)j * 512 + tid];
      acc1 += iv * ohW[(size_t)j * 512 + tid + 256];
    }
    onehot[(size_t)t * 512 + tid] = acc0;
    onehot[(size_t)t * 512 + tid + 256] = acc1;
  } else if (b < 640) {
    pack_body(Wo, Wop, 512, (long)(b - 512) * 256 + tid);
  } else if (b < 1152) {
    pack_body(W1, W1p, 2048, (long)(b - 640) * 256 + tid);
  } else if (b < 1664) {
    pack_body(W2, W2p, 512, (long)(b - 1152) * 256 + tid);
  } else {
    int which = b - 1664;
    const float* src = which == 0 ? Wv : (which == 1 ? Wk : Wq);
    unsigned short* dst = which == 0 ? Wv_b : (which == 1 ? Wk_b : Wq_b);
    float sc = which == 2 ? 0.06375871424f : 1.f;  // Wq: 1/sqrt(512)*log2(e)
#pragma unroll
    for (int j = 0; j < 4; ++j) {
      int i = tid * 16 + j * 4;
      float4 f = *(const float4*)(src + i);
      unsigned lo = (unsigned)f2bf(f.x * sc) | ((unsigned)f2bf(f.y * sc) << 16);
      unsigned hi = (unsigned)f2bf(f.z * sc) | ((unsigned)f2bf(f.w * sc) << 16);
      *(uint2*)(dst + i) = make_uint2(lo, hi);
    }
  }
}

// ---------------- fused projection GEMMs: grid 12288, which = bid>>12 -----
// which 0: V packed into MFMA-fragment order:
//   vP[(n*8+h)*32768 + ((c*16 + ks*4 + fj)*64 + l)*8 + j] =
//     V[t = c*128+ks*32+(l>>4)*8+j][d = fj*16+(l&15)]   (per (n,h))
// which 1: K row-major; which 2: Q (+onehot), row-major
__global__ __launch_bounds__(256) void proj_all(
    const float* __restrict__ value, const float* __restrict__ key_in,
    const float* __restrict__ query, const unsigned short* __restrict__ Wv_b,
    const unsigned short* __restrict__ Wk_b, const unsigned short* __restrict__ Wq_b,
    const float* __restrict__ onehot, unsigned short* __restrict__ vP,
    unsigned short* __restrict__ k_p, unsigned short* __restrict__ q_p) {
  __shared__ unsigned short As[64][40];
  __shared__ unsigned short Bs[64][40];   // Bs[col][k]
  __shared__ unsigned short Cs[64][72];   // V-pack bounce
  const int which = blockIdx.x >> 12;
  const int mb = blockIdx.x & 4095;
  const float* A = which == 0 ? value : (which == 1 ? key_in : query);
  const unsigned short* B = which == 0 ? Wv_b : (which == 1 ? Wk_b : Wq_b);
  unsigned short* C = which == 0 ? vP : (which == 1 ? k_p : q_p);
  const bool qin = (which == 2);
  const int m0 = mb * 64;
  const int tid = threadIdx.x, w = tid >> 6, l = tid & 63, lr = l & 15, lg = l >> 4;
  const int wr = (w >> 1) * 32, wc = (w & 1) * 32;
  const int aRow = (tid * 8) >> 5, aK = (tid * 8) & 31;
  const int bK = (tid * 8) >> 6, bCol = (tid * 8) & 63;
  f32x4 acc[2][2] = {};
  for (int kb = 0; kb < 64; kb += 32) {
    size_t fl = (size_t)(m0 + aRow) * 64 + kb + aK;
    float4 f0 = *(const float4*)(A + fl);
    float4 f1 = *(const float4*)(A + fl + 4);
    if (qin) {
      const float* oh = onehot + (fl & 262143);
      float4 o0 = *(const float4*)(oh);
      float4 o1 = *(const float4*)(oh + 4);
      f0.x += o0.x; f0.y += o0.y; f0.z += o0.z; f0.w += o0.w;
      f1.x += o1.x; f1.y += o1.y; f1.z += o1.z; f1.w += o1.w;
    }
    s16x8 av;
    av[0] = (short)f2bf(f0.x); av[1] = (short)f2bf(f0.y);
    av[2] = (short)f2bf(f0.z); av[3] = (short)f2bf(f0.w);
    av[4] = (short)f2bf(f1.x); av[5] = (short)f2bf(f1.y);
    av[6] = (short)f2bf(f1.z); av[7] = (short)f2bf(f1.w);
    *(s16x8*)&As[aRow][aK] = av;
    s16x8 bv = *(const s16x8*)(B + (size_t)(kb + bK) * 64 + bCol);
#pragma unroll
    for (int j = 0; j < 8; ++j) Bs[bCol + j][bK] = (unsigned short)bv[j];
    __syncthreads();
    s16x8 af0 = *(const s16x8*)&As[wr + lr][lg * 8];
    s16x8 af1 = *(const s16x8*)&As[wr + 16 + lr][lg * 8];
    s16x8 bf0 = *(const s16x8*)&Bs[wc + lr][lg * 8];
    s16x8 bf1 = *(const s16x8*)&Bs[wc + 16 + lr][lg * 8];
    acc[0][0] = __builtin_amdgcn_mfma_f32_16x16x32_bf16(af0, bf0, acc[0][0], 0, 0, 0);
    acc[0][1] = __builtin_amdgcn_mfma_f32_16x16x32_bf16(af0, bf1, acc[0][1], 0, 0, 0);
    acc[1][0] = __builtin_amdgcn_mfma_f32_16x16x32_bf16(af1, bf0, acc[1][0], 0, 0, 0);
    acc[1][1] = __builtin_amdgcn_mfma_f32_16x16x32_bf16(af1, bf1, acc[1][1], 0, 0, 0);
    __syncthreads();
  }
  if (which != 0) {
#pragma unroll
    for (int fi = 0; fi < 2; ++fi)
#pragma unroll
      for (int fj = 0; fj < 2; ++fj)
#pragma unroll
        for (int r = 0; r < 4; ++r) {
          int row = m0 + wr + fi * 16 + lg * 4 + r;
          int col = wc + fj * 16 + lr;
          C[(size_t)row * 64 + col] = f2bf(acc[fi][fj][r]);
        }
  } else {
#pragma unroll
    for (int fi = 0; fi < 2; ++fi)
#pragma unroll
      for (int fj = 0; fj < 2; ++fj)
#pragma unroll
        for (int r = 0; r < 4; ++r)
          Cs[wr + fi * 16 + lg * 4 + r][wc + fj * 16 + lr] = f2bf(acc[fi][fj][r]);
    __syncthreads();
    // rows m0..m0+63 encode (n*512+t)*8+h: t = t0 + r_local/8, h = r_local&7
    int nIdx = m0 >> 12, t0 = (m0 >> 3) & 511;
    int cc = t0 >> 7, ksv = (t0 >> 5) & 3, lgv = (t0 >> 3) & 3;
#pragma unroll
    for (int it = 0; it < 2; ++it) {
      int p = tid + it * 256;
      int hh = p >> 6, d = p & 63;
      s16x8 vv;
#pragma unroll
      for (int j = 0; j < 8; ++j) vv[j] = (short)Cs[j * 8 + hh][d];
      size_t dst = ((size_t)(nIdx * 8 + hh)) * 32768 +
                   (size_t)(((cc * 16 + ksv * 4 + (d >> 4)) * 64) + lgv * 16 + (d & 15)) * 8;
      *(s16x8*)(C + dst) = vv;
    }
  }
}

// ---------------- big GEMM: BK=64, XCD-swizzled 1D grid, B 2-deep prefetch
// RES: add bf16 residual (same ldc) in epilogue
template<bool RELU, bool OUTBF, bool RES>
__global__ __launch_bounds__(256) void gemmF(
    const unsigned short* __restrict__ A, int lda,
    const unsigned short* __restrict__ Bp, int ldbp, int nOff,
    const float* __restrict__ bias, void* __restrict__ Cout,
    const unsigned short* __restrict__ resid, int ldc,
    int M, int K, int nby) {
  __shared__ unsigned short As[2][8192];   // [buf][128 rows x 64 k] src-swizzled
  const int tid = threadIdx.x, w = tid >> 6, l = tid & 63, lr = l & 15, lg = l >> 4;
  const int nwg = gridDim.x;
  const int bid = (blockIdx.x & 7) * (nwg >> 3) + (blockIdx.x >> 3);
  const int bx = bid / nby, by = bid % nby;
  const int m0 = bx * 128;
  const int wr = (w >> 1) * 64, wc = (w & 1) * 64;
  const int srow = tid >> 3, sc8 = tid & 7;
  const int gcol = (sc8 ^ (srow & 7)) * 8;
  const unsigned short* Ag = A + (size_t)(m0 + srow) * lda + gcol;
  const size_t ldaa = (size_t)32 * lda;
  const unsigned short* Bg = Bp +
      ((size_t)(nOff >> 4) + by * 8 + (wc >> 4)) * 512 + lg * 128 + lr * 8;
  const size_t bks = (size_t)ldbp * 512;

  f32x4 acc[4][4] = {};
  s16x8 b0[4], b1[4];

#pragma unroll
  for (int it = 0; it < 4; ++it)
    async_copy16(&As[0][(it * 256 + tid) * 8], Ag + it * ldaa);
#pragma unroll
  for (int fj = 0; fj < 4; ++fj) {
    b0[fj] = *(const s16x8*)(Bg + fj * 512);
    b1[fj] = *(const s16x8*)(Bg + bks + fj * 512);
  }
  __syncthreads();

  int buf = 0;
  for (int kb = 0; kb < K; kb += 64) {
    int kn = (kb + 64 < K) ? kb + 64 : 0;
#pragma unroll
    for (int it = 0; it < 4; ++it)
      async_copy16(&As[buf ^ 1][(it * 256 + tid) * 8], Ag + kn + it * ldaa);
    s16x8 b0n[4];
    {
      const unsigned short* p = Bg + ((size_t)(kn >> 5)) * bks;
#pragma unroll
      for (int fj = 0; fj < 4; ++fj) b0n[fj] = *(const s16x8*)(p + fj * 512);
    }
    {
      s16x8 af[4];
#pragma unroll
      for (int fi = 0; fi < 4; ++fi) {
        int row = wr + fi * 16 + lr;
        af[fi] = *(const s16x8*)&As[buf][row * 64 + ((lg ^ (row & 7)) * 8)];
      }
#pragma unroll
      for (int fi = 0; fi < 4; ++fi)
#pragma unroll
        for (int fj = 0; fj < 4; ++fj)
          acc[fi][fj] = __builtin_amdgcn_mfma_f32_16x16x32_bf16(af[fi], b0[fj], acc[fi][fj], 0, 0, 0);
    }
    s16x8 b1n[4];
    {
      const unsigned short* p = Bg + ((size_t)((kn + 32) >> 5)) * bks;
#pragma unroll
      for (int fj = 0; fj < 4; ++fj) b1n[fj] = *(const s16x8*)(p + fj * 512);
    }
    {
      s16x8 af[4];
#pragma unroll
      for (int fi = 0; fi < 4; ++fi) {
        int row = wr + fi * 16 + lr;
        af[fi] = *(const s16x8*)&As[buf][row * 64 + (((4 + lg) ^ (row & 7)) * 8)];
      }
#pragma unroll
      for (int fi = 0; fi < 4; ++fi)
#pragma unroll
        for (int fj = 0; fj < 4; ++fj)
          acc[fi][fj] = __builtin_amdgcn_mfma_f32_16x16x32_bf16(af[fi], b1[fj], acc[fi][fj], 0, 0, 0);
    }
    __syncthreads();
#pragma unroll
    for (int fj = 0; fj < 4; ++fj) { b0[fj] = b0n[fj]; b1[fj] = b1n[fj]; }
    buf ^= 1;
  }

#pragma unroll
  for (int fj = 0; fj < 4; ++fj) {
    int colL = by * 128 + wc + fj * 16 + lr;
    float bv = bias[nOff + colL];
#pragma unroll
    for (int fi = 0; fi < 4; ++fi)
#pragma unroll
      for (int r = 0; r < 4; ++r) {
        int row = m0 + wr + fi * 16 + lg * 4 + r;
        size_t ci = (size_t)row * ldc + colL;
        float v = acc[fi][fj][r] + bv;
        if (RES) v += bf2f(resid[ci]);
        if (RELU) v = fmaxf(v, 0.f);
        if (OUTBF) ((unsigned short*)Cout)[ci] = f2bf(v);
        else ((float*)Cout)[ci] = v;
      }
  }
}

// ---------------- flash attention (R14 + XCD-chunked swizzle) -------------
// grid 2048; chunked remap: orig = (bid&7)*256 + bid>>3; qq = orig&3,
// g = orig>>2 -> each XCD's ~64 concurrent blocks cover 16 (n,h) panels
// x all 4 qq = 2MB K+V, fits the 4MB per-XCD L2 (panel fetched once).
// Q in regs; K staged in LDS per chunk (cooperative — inter-wave K reuse;
// R15 proved removing it costs 1.6x); V fragment-packed, hoisted to vreg at
// chunk top so L2 latency hides under QK^T + softmax; exp2-unit softmax.
__global__ __launch_bounds__(256, 2) void attn_kernel(
    const unsigned short* __restrict__ Qp, const unsigned short* __restrict__ Kp,
    const unsigned short* __restrict__ Vt, unsigned short* __restrict__ Out) {
  __shared__ unsigned short KS[128][72];
  __shared__ unsigned short P[4][16][132];
  const int orig = (blockIdx.x & 7) * 256 + (blockIdx.x >> 3);
  const int qq = orig & 3, g = orig >> 2, h = g & 7, n = g >> 3;
  const int tid = threadIdx.x, w = tid >> 6, l = tid & 63, lr = l & 15, lg = l >> 4;
  const int q0 = qq * 128;

  s16x8 qf[2][2];
#pragma unroll
  for (int rt = 0; rt < 2; ++rt) {
    const size_t qb = (((size_t)(n * 512 + q0 + w * 32 + rt * 16 + lr)) * 8 + h) * 64;
    qf[rt][0] = *(const s16x8*)(Qp + qb + lg * 8);
    qf[rt][1] = *(const s16x8*)(Qp + qb + 32 + lg * 8);
  }
  const unsigned short* Vfb = Vt + ((size_t)(n * 8 + h)) * 32768 + (size_t)l * 8;

  f32x4 oacc[2][4] = {};
  float m[2][4], lsum[2][4];
#pragma unroll
  for (int rt = 0; rt < 2; ++rt)
#pragma unroll
    for (int r = 0; r < 4; ++r) { m[rt][r] = -1e30f; lsum[rt][r] = 0.f; }
  s16x8 vreg[16];

  // prologue: stage K(0), hoist V(0)
#pragma unroll
  for (int it = 0; it < 4; ++it) {
    int idx = tid + it * 256;
    int rr = idx >> 3, dd = (idx & 7) * 8;
    *(s16x8*)&KS[rr][dd] =
        *(const s16x8*)(Kp + (((size_t)(n * 512 + rr)) * 8 + h) * 64 + dd);
  }
#pragma unroll
  for (int i = 0; i < 16; ++i)
    vreg[i] = *(const s16x8*)(Vfb + ((size_t)i << 9));
  __syncthreads();

  for (int c = 0; c < 4; ++c) {
    if (c) {
      __syncthreads();
#pragma unroll
      for (int it = 0; it < 4; ++it) {
        int idx = tid + it * 256;
        int rr = idx >> 3, dd = (idx & 7) * 8;
        *(s16x8*)&KS[rr][dd] =
            *(const s16x8*)(Kp + (((size_t)(n * 512 + c * 128 + rr)) * 8 + h) * 64 + dd);
      }
#pragma unroll
      for (int i = 0; i < 16; ++i)
        vreg[i] = *(const s16x8*)(Vfb + ((size_t)(c * 16 + i) << 9));
      __syncthreads();
    }
#pragma unroll
    for (int rt = 0; rt < 2; ++rt) {
      f32x4 sacc[8];
      __builtin_amdgcn_s_setprio(1);
#pragma unroll
      for (int f = 0; f < 8; ++f) {
        s16x8 b0 = *(const s16x8*)&KS[f * 16 + lr][lg * 8];
        s16x8 b1 = *(const s16x8*)&KS[f * 16 + lr][32 + lg * 8];
        f32x4 a = {};
        a = __builtin_amdgcn_mfma_f32_16x16x32_bf16(qf[rt][0], b0, a, 0, 0, 0);
        a = __builtin_amdgcn_mfma_f32_16x16x32_bf16(qf[rt][1], b1, a, 0, 0, 0);
        sacc[f] = a;
      }
      __builtin_amdgcn_s_setprio(0);

      float fs[4];
#pragma unroll
      for (int r = 0; r < 4; ++r) {
        float cm = sacc[0][r];
#pragma unroll
        for (int f = 1; f < 8; ++f) cm = fmaxf(cm, sacc[f][r]);
#pragma unroll
        for (int mk = 1; mk < 16; mk <<= 1) cm = fmaxf(cm, __shfl_xor(cm, mk));
        float mn = fmaxf(m[rt][r], cm);
        fs[r] = __builtin_amdgcn_exp2f(m[rt][r] - mn);   // exp2 units
        m[rt][r] = mn;
        unsigned pa = lds_addr(&P[w][lg * 4 + r][lr]);
        float cs = 0.f;
#pragma unroll
        for (int f = 0; f < 8; ++f) {
          float p = __builtin_amdgcn_exp2f(sacc[f][r] - mn);
          asm volatile("ds_write_b16_d16_hi %0, %1 offset:%2"
                       :: "v"(pa), "v"(p), "i"(f * 32) : "memory");
          cs += p;
        }
#pragma unroll
        for (int mk = 1; mk < 16; mk <<= 1) cs += __shfl_xor(cs, mk);
        lsum[rt][r] = lsum[rt][r] * fs[r] + cs;
      }
#pragma unroll
      for (int fj = 0; fj < 4; ++fj)
#pragma unroll
        for (int r = 0; r < 4; ++r) oacc[rt][fj][r] *= fs[r];

      asm volatile("s_waitcnt lgkmcnt(0)" ::: "memory");
      __builtin_amdgcn_sched_barrier(0);
      __builtin_amdgcn_s_setprio(1);
#pragma unroll
      for (int ks = 0; ks < 4; ++ks) {
        s16x8 pa = *(const s16x8*)&P[w][lr][ks * 32 + lg * 8];
#pragma unroll
        for (int fj = 0; fj < 4; ++fj)
          oacc[rt][fj] = __builtin_amdgcn_mfma_f32_16x16x32_bf16(pa, vreg[ks * 4 + fj], oacc[rt][fj], 0, 0, 0);
      }
      __builtin_amdgcn_s_setprio(0);
    }
  }

#pragma unroll
  for (int rt = 0; rt < 2; ++rt)
#pragma unroll
    for (int fj = 0; fj < 4; ++fj)
#pragma unroll
      for (int r = 0; r < 4; ++r) {
        int qrow = q0 + w * 32 + rt * 16 + lg * 4 + r;
        Out[((size_t)(n * 512 + qrow)) * 512 + h * 64 + fj * 16 + lr] =
            f2bf(oacc[rt][fj][r] / lsum[rt][r]);
      }
}

// ---------------- layernorm: 1 wave per 512-elem row, fused residual ------
// RES: add residual R (RBF selects bf16/f32); QIN: add onehot row
template<bool XBF, bool RES, bool RBF, bool QIN, bool OUTBF>
__global__ __launch_bounds__(256) void ln_kernel(const void* __restrict__ Xv,
    const void* __restrict__ Rv, const float* __restrict__ onehot,
    const float* __restrict__ g, const float* __restrict__ bb,
    void* __restrict__ outv) {
  int row = blockIdx.x * 4 + (threadIdx.x >> 6);
  int l = threadIdx.x & 63;
  size_t base = (size_t)row * 512 + l * 8;
  float v[8];
  if (XBF) {
    s16x8 xv = *(const s16x8*)((const unsigned short*)Xv + base);
#pragma unroll
    for (int j = 0; j < 8; ++j) v[j] = bf2f((unsigned short)xv[j]);
  } else {
    const float* X = (const float*)Xv;
    float4 x0 = *(const float4*)(X + base);
    float4 x1 = *(const float4*)(X + base + 4);
    v[0] = x0.x; v[1] = x0.y; v[2] = x0.z; v[3] = x0.w;
    v[4] = x1.x; v[5] = x1.y; v[6] = x1.z; v[7] = x1.w;
  }
  if (RES) {
    if (RBF) {
      s16x8 rv = *(const s16x8*)((const unsigned short*)Rv + base);
#pragma unroll
      for (int j = 0; j < 8; ++j) v[j] += bf2f((unsigned short)rv[j]);
    } else {
      const float* R = (const float*)Rv;
      float4 r0 = *(const float4*)(R + base);
      float4 r1 = *(const float4*)(R + base + 4);
      v[0] += r0.x; v[1] += r0.y; v[2] += r0.z; v[3] += r0.w;
      v[4] += r1.x; v[5] += r1.y; v[6] += r1.z; v[7] += r1.w;
    }
  }
  if (QIN) {
    size_t ob = (size_t)(row & 511) * 512 + l * 8;
    float4 o0 = *(const float4*)(onehot + ob);
    float4 o1 = *(const float4*)(onehot + ob + 4);
    v[0] += o0.x; v[1] += o0.y; v[2] += o0.z; v[3] += o0.w;
    v[4] += o1.x; v[5] += o1.y; v[6] += o1.z; v[7] += o1.w;
  }
  float s = 0.f, ss = 0.f;
#pragma unroll
  for (int j = 0; j < 8; ++j) { s += v[j]; ss += v[j] * v[j]; }
#pragma unroll
  for (int mk = 1; mk < 64; mk <<= 1) { s += __shfl_xor(s, mk); ss += __shfl_xor(ss, mk); }
  float mu = s * (1.f / 512.f);
  float inv = rsqrtf(ss * (1.f / 512.f) - mu * mu + 1e-5f);
#pragma unroll
  for (int j = 0; j < 8; ++j) {
    int e = l * 8 + j;
    float y = (v[j] - mu) * inv * g[e] + bb[e];
    if (OUTBF) ((unsigned short*)outv)[base + j] = f2bf(y);
    else ((float*)outv)[base + j] = y;
  }
}

extern "C" void kernel_launch(void* const* d_in, const int* in_sizes, int n_in,
                              void* d_out, int out_size, void* d_ws, size_t ws_size,
                              hipStream_t stream) {
  const float* value  = (const float*)d_in[0];
  const float* key_in = (const float*)d_in[1];
  const float* query  = (const float*)d_in[2];
  const int*   pi     = (const int*)d_in[3];
  const float* I_mat  = (const float*)d_in[4];
  const float* ohW    = (const float*)d_in[5];
  const float* ohb    = (const float*)d_in[6];
  const float* Wv     = (const float*)d_in[7];
  const float* Wk     = (const float*)d_in[8];
  const float* Wq     = (const float*)d_in[9];
  const float* Wo     = (const float*)d_in[10];
  const float* bo     = (const float*)d_in[11];
  const float* g1     = (const float*)d_in[12];
  const float* b1     = (const float*)d_in[13];
  const float* g2     = (const float*)d_in[14];
  const float* b2     = (const float*)d_in[15];
  const float* W1     = (const float*)d_in[16];
  const float* bf1    = (const float*)d_in[17];
  const float* W2     = (const float*)d_in[18];
  const float* bf2    = (const float*)d_in[19];

  char* ws = (char*)d_ws;
  const size_t MB = 1024 * 1024;
  unsigned short* q_p  = (unsigned short*)d_out;      // d_out as scratch
  unsigned short* k_p  = q_p + 16777216;
  unsigned short* vP     = (unsigned short*)(ws + 0);        // 32MB, fragment-packed
  unsigned short* attn_o = (unsigned short*)(ws + 32 * MB);  // 32MB
  unsigned short* x_b    = (unsigned short*)(ws + 64 * MB);  // 32MB
  unsigned short* ff1h   = (unsigned short*)(ws + 0);        // 64MB half (aliases vP/attn_o)
  float*          onehot = (float*)(ws + 96 * MB);           // 1MB
  unsigned short* Wv_b   = (unsigned short*)(ws + 97 * MB);
  unsigned short* Wk_b   = Wv_b + 4096;
  unsigned short* Wq_b   = Wk_b + 4096;
  unsigned short* Wop    = Wq_b + 4096;      // 512KB packed
  unsigned short* W1p    = Wop + 262144;     // 2MB packed
  unsigned short* W2p    = W1p + 1048576;    // 2MB packed

  prep_kernel<<<1667, 256, 0, stream>>>(pi, I_mat, ohW, ohb, onehot,
      Wv, Wk, Wq, Wv_b, Wk_b, Wq_b, Wo, W1, W2, Wop, W1p, W2p);

  proj_all<<<12288, 256, 0, stream>>>(value, key_in, query,
      Wv_b, Wk_b, Wq_b, onehot, vP, k_p, q_p);

  attn_kernel<<<2048, 256, 0, stream>>>(q_p, k_p, vP, attn_o);

  // Wo: x_b(bf16) = attn_o @ Wo + bo
  gemmF<false, true, false><<<1024, 256, 0, stream>>>(
      attn_o, 512, Wop, 32, 0, bo, x_b, nullptr, 512, 32768, 512, 4);
  // LN1 in place on x_b, residual = query + onehot
  ln_kernel<true, true, false, true, true><<<8192, 256, 0, stream>>>(
      x_b, query, onehot, g1, b1, x_b);

  // FFN split over 2 row-halves (M=16384 each); FFN2 fuses +x residual
  for (int hf = 0; hf < 2; ++hf) {
    const unsigned short* xh = x_b + (size_t)hf * 16384 * 512;
    gemmF<true, true, false><<<2048, 256, 0, stream>>>(
        xh, 512, W1p, 128, 0, bf1, ff1h, nullptr, 2048, 16384, 512, 16);
    gemmF<false, false, true><<<512, 256, 0, stream>>>(
        ff1h, 2048, W2p, 32, 0, bf2, (float*)d_out + (size_t)hf * 16384 * 512,
        xh, 512, 16384, 2048, 4);
  }
  // LN2: X = d_out f32 (residual already added) -> d_out in place
  ln_kernel<false, false, false, false, false><<<8192, 256, 0, stream>>>(
      d_out, nullptr, nullptr, g2, b2, d_out);
}

// Round 18
// 427.827 us; speedup vs baseline: 1.1562x; 1.0124x over previous
//
#include <hip/hip_runtime.h>

typedef __attribute__((ext_vector_type(8))) short s16x8;
typedef __attribute__((ext_vector_type(4))) float f32x4;

#define TN 288

__device__ __forceinline__ unsigned short f2bf(float f) {
  union { float f; unsigned u; } v; v.f = f;
  unsigned r = v.u + 0x7fffu + ((v.u >> 16) & 1u);
  return (unsigned short)(r >> 16);
}
__device__ __forceinline__ float bf2f(unsigned short u) {
  union { float f; unsigned u; } v; v.u = ((unsigned)u) << 16;
  return v.f;
}
__device__ __forceinline__ unsigned lds_addr(const void* p) {
  return (unsigned)(unsigned long long)(const __attribute__((address_space(3))) char*)p;
}
__device__ __forceinline__ void async_copy16(unsigned short* lds, const unsigned short* g) {
  __builtin_amdgcn_global_load_lds(
      (const __attribute__((address_space(1))) unsigned int*)g,
      (__attribute__((address_space(3))) unsigned int*)lds, 16, 0, 0);
}

// ---------------- fused prep: onehot + weight casts + packs (1 launch) ----
__device__ __forceinline__ void pack_body(const float* __restrict__ W,
    unsigned short* __restrict__ out, int N, long t) {
  int lr = (int)(t & 15);
  int lg = (int)((t >> 4) & 3);
  long g6 = t >> 6;
  int nt = N >> 4;
  int n16 = (int)(g6 % nt);
  int kb = (int)(g6 / nt) << 5;
  int k = kb + lg * 8;
  int col = n16 * 16 + lr;
  s16x8 v;
#pragma unroll
  for (int j = 0; j < 8; ++j) v[j] = (short)f2bf(W[(size_t)(k + j) * N + col]);
  *(s16x8*)(out + t * 8) = v;
}

__global__ __launch_bounds__(256) void prep_kernel(const int* __restrict__ pi,
    const float* __restrict__ I_mat, const float* __restrict__ ohW,
    const float* __restrict__ ohb, float* __restrict__ onehot,
    const float* __restrict__ Wv, const float* __restrict__ Wk,
    const float* __restrict__ Wq, unsigned short* __restrict__ Wv_b,
    unsigned short* __restrict__ Wk_b, unsigned short* __restrict__ Wq_b,
    const float* __restrict__ Wo, const float* __restrict__ W1,
    const float* __restrict__ W2, unsigned short* __restrict__ Wop,
    unsigned short* __restrict__ W1p, unsigned short* __restrict__ W2p) {
  int b = blockIdx.x, tid = threadIdx.x;
  if (b < 512) {
    int t = b;
    int r = (pi[0] + t) % TN;
    float acc0 = ohb[tid], acc1 = ohb[tid + 256];
    const float* Ir = I_mat + (size_t)r * TN;
    for (int j = 0; j < TN; ++j) {
      float iv = Ir[j];
      acc0 += iv * ohW[(size_t)j * 512 + tid];
      acc1 += iv * ohW[(size_t)j * 512 + tid + 256];
    }
    onehot[(size_t)t * 512 + tid] = acc0;
    onehot[(size_t)t * 512 + tid + 256] = acc1;
  } else if (b < 640) {
    pack_body(Wo, Wop, 512, (long)(b - 512) * 256 + tid);
  } else if (b < 1152) {
    pack_body(W1, W1p, 2048, (long)(b - 640) * 256 + tid);
  } else if (b < 1664) {
    pack_body(W2, W2p, 512, (long)(b - 1152) * 256 + tid);
  } else {
    int which = b - 1664;
    const float* src = which == 0 ? Wv : (which == 1 ? Wk : Wq);
    unsigned short* dst = which == 0 ? Wv_b : (which == 1 ? Wk_b : Wq_b);
    float sc = which == 2 ? 0.06375871424f : 1.f;  // Wq: 1/sqrt(512)*log2(e)
#pragma unroll
    for (int j = 0; j < 4; ++j) {
      int i = tid * 16 + j * 4;
      float4 f = *(const float4*)(src + i);
      unsigned lo = (unsigned)f2bf(f.x * sc) | ((unsigned)f2bf(f.y * sc) << 16);
      unsigned hi = (unsigned)f2bf(f.z * sc) | ((unsigned)f2bf(f.w * sc) << 16);
      *(uint2*)(dst + i) = make_uint2(lo, hi);
    }
  }
}

// ---------------- fused projection GEMMs: grid 12288, which = bid>>12 -----
// which 0: V packed into MFMA-fragment order:
//   vP[(n*8+h)*32768 + ((c*16 + ks*4 + fj)*64 + l)*8 + j] =
//     V[t = c*128+ks*32+(l>>4)*8+j][d = fj*16+(l&15)]   (per (n,h))
// which 1: K row-major; which 2: Q (+onehot), row-major
__global__ __launch_bounds__(256) void proj_all(
    const float* __restrict__ value, const float* __restrict__ key_in,
    const float* __restrict__ query, const unsigned short* __restrict__ Wv_b,
    const unsigned short* __restrict__ Wk_b, const unsigned short* __restrict__ Wq_b,
    const float* __restrict__ onehot, unsigned short* __restrict__ vP,
    unsigned short* __restrict__ k_p, unsigned short* __restrict__ q_p) {
  __shared__ unsigned short As[64][40];
  __shared__ unsigned short Bs[64][40];   // Bs[col][k]
  __shared__ unsigned short Cs[64][72];   // V-pack bounce
  const int which = blockIdx.x >> 12;
  const int mb = blockIdx.x & 4095;
  const float* A = which == 0 ? value : (which == 1 ? key_in : query);
  const unsigned short* B = which == 0 ? Wv_b : (which == 1 ? Wk_b : Wq_b);
  unsigned short* C = which == 0 ? vP : (which == 1 ? k_p : q_p);
  const bool qin = (which == 2);
  const int m0 = mb * 64;
  const int tid = threadIdx.x, w = tid >> 6, l = tid & 63, lr = l & 15, lg = l >> 4;
  const int wr = (w >> 1) * 32, wc = (w & 1) * 32;
  const int aRow = (tid * 8) >> 5, aK = (tid * 8) & 31;
  const int bK = (tid * 8) >> 6, bCol = (tid * 8) & 63;
  f32x4 acc[2][2] = {};
  for (int kb = 0; kb < 64; kb += 32) {
    size_t fl = (size_t)(m0 + aRow) * 64 + kb + aK;
    float4 f0 = *(const float4*)(A + fl);
    float4 f1 = *(const float4*)(A + fl + 4);
    if (qin) {
      const float* oh = onehot + (fl & 262143);
      float4 o0 = *(const float4*)(oh);
      float4 o1 = *(const float4*)(oh + 4);
      f0.x += o0.x; f0.y += o0.y; f0.z += o0.z; f0.w += o0.w;
      f1.x += o1.x; f1.y += o1.y; f1.z += o1.z; f1.w += o1.w;
    }
    s16x8 av;
    av[0] = (short)f2bf(f0.x); av[1] = (short)f2bf(f0.y);
    av[2] = (short)f2bf(f0.z); av[3] = (short)f2bf(f0.w);
    av[4] = (short)f2bf(f1.x); av[5] = (short)f2bf(f1.y);
    av[6] = (short)f2bf(f1.z); av[7] = (short)f2bf(f1.w);
    *(s16x8*)&As[aRow][aK] = av;
    s16x8 bv = *(const s16x8*)(B + (size_t)(kb + bK) * 64 + bCol);
#pragma unroll
    for (int j = 0; j < 8; ++j) Bs[bCol + j][bK] = (unsigned short)bv[j];
    __syncthreads();
    s16x8 af0 = *(const s16x8*)&As[wr + lr][lg * 8];
    s16x8 af1 = *(const s16x8*)&As[wr + 16 + lr][lg * 8];
    s16x8 bf0 = *(const s16x8*)&Bs[wc + lr][lg * 8];
    s16x8 bf1 = *(const s16x8*)&Bs[wc + 16 + lr][lg * 8];
    acc[0][0] = __builtin_amdgcn_mfma_f32_16x16x32_bf16(af0, bf0, acc[0][0], 0, 0, 0);
    acc[0][1] = __builtin_amdgcn_mfma_f32_16x16x32_bf16(af0, bf1, acc[0][1], 0, 0, 0);
    acc[1][0] = __builtin_amdgcn_mfma_f32_16x16x32_bf16(af1, bf0, acc[1][0], 0, 0, 0);
    acc[1][1] = __builtin_amdgcn_mfma_f32_16x16x32_bf16(af1, bf1, acc[1][1], 0, 0, 0);
    __syncthreads();
  }
  if (which != 0) {
#pragma unroll
    for (int fi = 0; fi < 2; ++fi)
#pragma unroll
      for (int fj = 0; fj < 2; ++fj)
#pragma unroll
        for (int r = 0; r < 4; ++r) {
          int row = m0 + wr + fi * 16 + lg * 4 + r;
          int col = wc + fj * 16 + lr;
          C[(size_t)row * 64 + col] = f2bf(acc[fi][fj][r]);
        }
  } else {
#pragma unroll
    for (int fi = 0; fi < 2; ++fi)
#pragma unroll
      for (int fj = 0; fj < 2; ++fj)
#pragma unroll
        for (int r = 0; r < 4; ++r)
          Cs[wr + fi * 16 + lg * 4 + r][wc + fj * 16 + lr] = f2bf(acc[fi][fj][r]);
    __syncthreads();
    // rows m0..m0+63 encode (n*512+t)*8+h: t = t0 + r_local/8, h = r_local&7
    int nIdx = m0 >> 12, t0 = (m0 >> 3) & 511;
    int cc = t0 >> 7, ksv = (t0 >> 5) & 3, lgv = (t0 >> 3) & 3;
#pragma unroll
    for (int it = 0; it < 2; ++it) {
      int p = tid + it * 256;
      int hh = p >> 6, d = p & 63;
      s16x8 vv;
#pragma unroll
      for (int j = 0; j < 8; ++j) vv[j] = (short)Cs[j * 8 + hh][d];
      size_t dst = ((size_t)(nIdx * 8 + hh)) * 32768 +
                   (size_t)(((cc * 16 + ksv * 4 + (d >> 4)) * 64) + lgv * 16 + (d & 15)) * 8;
      *(s16x8*)(C + dst) = vv;
    }
  }
}

// ---------------- big GEMM: BK=64, XCD-swizzled 1D grid, B 2-deep prefetch
// RES: add bf16 residual (same ldc) in epilogue
template<bool RELU, bool OUTBF, bool RES>
__global__ __launch_bounds__(256) void gemmF(
    const unsigned short* __restrict__ A, int lda,
    const unsigned short* __restrict__ Bp, int ldbp, int nOff,
    const float* __restrict__ bias, void* __restrict__ Cout,
    const unsigned short* __restrict__ resid, int ldc,
    int M, int K, int nby) {
  __shared__ unsigned short As[2][8192];   // [buf][128 rows x 64 k] src-swizzled
  const int tid = threadIdx.x, w = tid >> 6, l = tid & 63, lr = l & 15, lg = l >> 4;
  const int nwg = gridDim.x;
  const int bid = (blockIdx.x & 7) * (nwg >> 3) + (blockIdx.x >> 3);
  const int bx = bid / nby, by = bid % nby;
  const int m0 = bx * 128;
  const int wr = (w >> 1) * 64, wc = (w & 1) * 64;
  const int srow = tid >> 3, sc8 = tid & 7;
  const int gcol = (sc8 ^ (srow & 7)) * 8;
  const unsigned short* Ag = A + (size_t)(m0 + srow) * lda + gcol;
  const size_t ldaa = (size_t)32 * lda;
  const unsigned short* Bg = Bp +
      ((size_t)(nOff >> 4) + by * 8 + (wc >> 4)) * 512 + lg * 128 + lr * 8;
  const size_t bks = (size_t)ldbp * 512;

  f32x4 acc[4][4] = {};
  s16x8 b0[4], b1[4];

#pragma unroll
  for (int it = 0; it < 4; ++it)
    async_copy16(&As[0][(it * 256 + tid) * 8], Ag + it * ldaa);
#pragma unroll
  for (int fj = 0; fj < 4; ++fj) {
    b0[fj] = *(const s16x8*)(Bg + fj * 512);
    b1[fj] = *(const s16x8*)(Bg + bks + fj * 512);
  }
  __syncthreads();

  int buf = 0;
  for (int kb = 0; kb < K; kb += 64) {
    int kn = (kb + 64 < K) ? kb + 64 : 0;
#pragma unroll
    for (int it = 0; it < 4; ++it)
      async_copy16(&As[buf ^ 1][(it * 256 + tid) * 8], Ag + kn + it * ldaa);
    s16x8 b0n[4];
    {
      const unsigned short* p = Bg + ((size_t)(kn >> 5)) * bks;
#pragma unroll
      for (int fj = 0; fj < 4; ++fj) b0n[fj] = *(const s16x8*)(p + fj * 512);
    }
    {
      s16x8 af[4];
#pragma unroll
      for (int fi = 0; fi < 4; ++fi) {
        int row = wr + fi * 16 + lr;
        af[fi] = *(const s16x8*)&As[buf][row * 64 + ((lg ^ (row & 7)) * 8)];
      }
#pragma unroll
      for (int fi = 0; fi < 4; ++fi)
#pragma unroll
        for (int fj = 0; fj < 4; ++fj)
          acc[fi][fj] = __builtin_amdgcn_mfma_f32_16x16x32_bf16(af[fi], b0[fj], acc[fi][fj], 0, 0, 0);
    }
    s16x8 b1n[4];
    {
      const unsigned short* p = Bg + ((size_t)((kn + 32) >> 5)) * bks;
#pragma unroll
      for (int fj = 0; fj < 4; ++fj) b1n[fj] = *(const s16x8*)(p + fj * 512);
    }
    {
      s16x8 af[4];
#pragma unroll
      for (int fi = 0; fi < 4; ++fi) {
        int row = wr + fi * 16 + lr;
        af[fi] = *(const s16x8*)&As[buf][row * 64 + (((4 + lg) ^ (row & 7)) * 8)];
      }
#pragma unroll
      for (int fi = 0; fi < 4; ++fi)
#pragma unroll
        for (int fj = 0; fj < 4; ++fj)
          acc[fi][fj] = __builtin_amdgcn_mfma_f32_16x16x32_bf16(af[fi], b1[fj], acc[fi][fj], 0, 0, 0);
    }
    __syncthreads();
#pragma unroll
    for (int fj = 0; fj < 4; ++fj) { b0[fj] = b0n[fj]; b1[fj] = b1n[fj]; }
    buf ^= 1;
  }

#pragma unroll
  for (int fj = 0; fj < 4; ++fj) {
    int colL = by * 128 + wc + fj * 16 + lr;
    float bv = bias[nOff + colL];
#pragma unroll
    for (int fi = 0; fi < 4; ++fi)
#pragma unroll
      for (int r = 0; r < 4; ++r) {
        int row = m0 + wr + fi * 16 + lg * 4 + r;
        size_t ci = (size_t)row * ldc + colL;
        float v = acc[fi][fj][r] + bv;
        if (RES) v += bf2f(resid[ci]);
        if (RELU) v = fmaxf(v, 0.f);
        if (OUTBF) ((unsigned short*)Cout)[ci] = f2bf(v);
        else ((float*)Cout)[ci] = v;
      }
  }
}

// ---------------- flash attention (R17 + T14 async K-stage split) ---------
// grid 2048; chunked XCD remap (R17: FETCH 147->49MB). Q in regs; K staged
// in LDS per chunk, but the GLOBAL loads for chunk c+1 are issued at the
// TOP of chunk c's compute (kreg, 16 VGPR) so their latency hides under
// ~3000cy of QK^T/softmax/PV; only the fast ds_writes sit in the barrier
// window. V fragment-packed, loaded at compute top (first use ~700cy later).
__global__ __launch_bounds__(256, 2) void attn_kernel(
    const unsigned short* __restrict__ Qp, const unsigned short* __restrict__ Kp,
    const unsigned short* __restrict__ Vt, unsigned short* __restrict__ Out) {
  __shared__ unsigned short KS[128][72];
  __shared__ unsigned short P[4][16][132];
  const int orig = (blockIdx.x & 7) * 256 + (blockIdx.x >> 3);
  const int qq = orig & 3, g = orig >> 2, h = g & 7, n = g >> 3;
  const int tid = threadIdx.x, w = tid >> 6, l = tid & 63, lr = l & 15, lg = l >> 4;
  const int q0 = qq * 128;

  s16x8 qf[2][2];
#pragma unroll
  for (int rt = 0; rt < 2; ++rt) {
    const size_t qb = (((size_t)(n * 512 + q0 + w * 32 + rt * 16 + lr)) * 8 + h) * 64;
    qf[rt][0] = *(const s16x8*)(Qp + qb + lg * 8);
    qf[rt][1] = *(const s16x8*)(Qp + qb + 32 + lg * 8);
  }
  const unsigned short* Vfb = Vt + ((size_t)(n * 8 + h)) * 32768 + (size_t)l * 8;
  const int srr = tid >> 3, sdd = (tid & 7) * 8;   // staging slot (it stride 32 rows)

  f32x4 oacc[2][4] = {};
  float m[2][4], lsum[2][4];
#pragma unroll
  for (int rt = 0; rt < 2; ++rt)
#pragma unroll
    for (int r = 0; r < 4; ++r) { m[rt][r] = -1e30f; lsum[rt][r] = 0.f; }
  s16x8 vreg[16], kreg[4];

  // prologue: stage K(0) direct
#pragma unroll
  for (int it = 0; it < 4; ++it)
    *(s16x8*)&KS[it * 32 + srr][sdd] =
        *(const s16x8*)(Kp + (((size_t)(n * 512 + it * 32 + srr)) * 8 + h) * 64 + sdd);
  __syncthreads();

  for (int c = 0; c < 4; ++c) {
    // issue-early: next chunk's K into registers (latency hides under compute)
    if (c < 3) {
#pragma unroll
      for (int it = 0; it < 4; ++it)
        kreg[it] = *(const s16x8*)(
            Kp + (((size_t)(n * 512 + (c + 1) * 128 + it * 32 + srr)) * 8 + h) * 64 + sdd);
    }
    // V(c) loads: first PV use is after QK^T+softmax (~700cy) — covered
#pragma unroll
    for (int i = 0; i < 16; ++i)
      vreg[i] = *(const s16x8*)(Vfb + ((size_t)(c * 16 + i) << 9));

#pragma unroll
    for (int rt = 0; rt < 2; ++rt) {
      f32x4 sacc[8];
      __builtin_amdgcn_s_setprio(1);
#pragma unroll
      for (int f = 0; f < 8; ++f) {
        s16x8 b0 = *(const s16x8*)&KS[f * 16 + lr][lg * 8];
        s16x8 b1 = *(const s16x8*)&KS[f * 16 + lr][32 + lg * 8];
        f32x4 a = {};
        a = __builtin_amdgcn_mfma_f32_16x16x32_bf16(qf[rt][0], b0, a, 0, 0, 0);
        a = __builtin_amdgcn_mfma_f32_16x16x32_bf16(qf[rt][1], b1, a, 0, 0, 0);
        sacc[f] = a;
      }
      __builtin_amdgcn_s_setprio(0);

      float fs[4];
#pragma unroll
      for (int r = 0; r < 4; ++r) {
        float cm = sacc[0][r];
#pragma unroll
        for (int f = 1; f < 8; ++f) cm = fmaxf(cm, sacc[f][r]);
#pragma unroll
        for (int mk = 1; mk < 16; mk <<= 1) cm = fmaxf(cm, __shfl_xor(cm, mk));
        float mn = fmaxf(m[rt][r], cm);
        fs[r] = __builtin_amdgcn_exp2f(m[rt][r] - mn);   // exp2 units
        m[rt][r] = mn;
        unsigned pa = lds_addr(&P[w][lg * 4 + r][lr]);
        float cs = 0.f;
#pragma unroll
        for (int f = 0; f < 8; ++f) {
          float p = __builtin_amdgcn_exp2f(sacc[f][r] - mn);
          asm volatile("ds_write_b16_d16_hi %0, %1 offset:%2"
                       :: "v"(pa), "v"(p), "i"(f * 32) : "memory");
          cs += p;
        }
#pragma unroll
        for (int mk = 1; mk < 16; mk <<= 1) cs += __shfl_xor(cs, mk);
        lsum[rt][r] = lsum[rt][r] * fs[r] + cs;
      }
#pragma unroll
      for (int fj = 0; fj < 4; ++fj)
#pragma unroll
        for (int r = 0; r < 4; ++r) oacc[rt][fj][r] *= fs[r];

      asm volatile("s_waitcnt lgkmcnt(0)" ::: "memory");
      __builtin_amdgcn_sched_barrier(0);
      __builtin_amdgcn_s_setprio(1);
#pragma unroll
      for (int ks = 0; ks < 4; ++ks) {
        s16x8 pa = *(const s16x8*)&P[w][lr][ks * 32 + lg * 8];
#pragma unroll
        for (int fj = 0; fj < 4; ++fj)
          oacc[rt][fj] = __builtin_amdgcn_mfma_f32_16x16x32_bf16(pa, vreg[ks * 4 + fj], oacc[rt][fj], 0, 0, 0);
      }
      __builtin_amdgcn_s_setprio(0);
    }

    __syncthreads();           // all waves done reading KS(c)
    if (c < 3) {
      // write-late: fast LDS writes only in the barrier window
#pragma unroll
      for (int it = 0; it < 4; ++it)
        *(s16x8*)&KS[it * 32 + srr][sdd] = kreg[it];
    }
    __syncthreads();           // KS(c+1) visible
  }

#pragma unroll
  for (int rt = 0; rt < 2; ++rt)
#pragma unroll
    for (int fj = 0; fj < 4; ++fj)
#pragma unroll
      for (int r = 0; r < 4; ++r) {
        int qrow = q0 + w * 32 + rt * 16 + lg * 4 + r;
        Out[((size_t)(n * 512 + qrow)) * 512 + h * 64 + fj * 16 + lr] =
            f2bf(oacc[rt][fj][r] / lsum[rt][r]);
      }
}

// ---------------- layernorm: 1 wave per 512-elem row, fused residual ------
// RES: add residual R (RBF selects bf16/f32); QIN: add onehot row
template<bool XBF, bool RES, bool RBF, bool QIN, bool OUTBF>
__global__ __launch_bounds__(256) void ln_kernel(const void* __restrict__ Xv,
    const void* __restrict__ Rv, const float* __restrict__ onehot,
    const float* __restrict__ g, const float* __restrict__ bb,
    void* __restrict__ outv) {
  int row = blockIdx.x * 4 + (threadIdx.x >> 6);
  int l = threadIdx.x & 63;
  size_t base = (size_t)row * 512 + l * 8;
  float v[8];
  if (XBF) {
    s16x8 xv = *(const s16x8*)((const unsigned short*)Xv + base);
#pragma unroll
    for (int j = 0; j < 8; ++j) v[j] = bf2f((unsigned short)xv[j]);
  } else {
    const float* X = (const float*)Xv;
    float4 x0 = *(const float4*)(X + base);
    float4 x1 = *(const float4*)(X + base + 4);
    v[0] = x0.x; v[1] = x0.y; v[2] = x0.z; v[3] = x0.w;
    v[4] = x1.x; v[5] = x1.y; v[6] = x1.z; v[7] = x1.w;
  }
  if (RES) {
    if (RBF) {
      s16x8 rv = *(const s16x8*)((const unsigned short*)Rv + base);
#pragma unroll
      for (int j = 0; j < 8; ++j) v[j] += bf2f((unsigned short)rv[j]);
    } else {
      const float* R = (const float*)Rv;
      float4 r0 = *(const float4*)(R + base);
      float4 r1 = *(const float4*)(R + base + 4);
      v[0] += r0.x; v[1] += r0.y; v[2] += r0.z; v[3] += r0.w;
      v[4] += r1.x; v[5] += r1.y; v[6] += r1.z; v[7] += r1.w;
    }
  }
  if (QIN) {
    size_t ob = (size_t)(row & 511) * 512 + l * 8;
    float4 o0 = *(const float4*)(onehot + ob);
    float4 o1 = *(const float4*)(onehot + ob + 4);
    v[0] += o0.x; v[1] += o0.y; v[2] += o0.z; v[3] += o0.w;
    v[4] += o1.x; v[5] += o1.y; v[6] += o1.z; v[7] += o1.w;
  }
  float s = 0.f, ss = 0.f;
#pragma unroll
  for (int j = 0; j < 8; ++j) { s += v[j]; ss += v[j] * v[j]; }
#pragma unroll
  for (int mk = 1; mk < 64; mk <<= 1) { s += __shfl_xor(s, mk); ss += __shfl_xor(ss, mk); }
  float mu = s * (1.f / 512.f);
  float inv = rsqrtf(ss * (1.f / 512.f) - mu * mu + 1e-5f);
#pragma unroll
  for (int j = 0; j < 8; ++j) {
    int e = l * 8 + j;
    float y = (v[j] - mu) * inv * g[e] + bb[e];
    if (OUTBF) ((unsigned short*)outv)[base + j] = f2bf(y);
    else ((float*)outv)[base + j] = y;
  }
}

extern "C" void kernel_launch(void* const* d_in, const int* in_sizes, int n_in,
                              void* d_out, int out_size, void* d_ws, size_t ws_size,
                              hipStream_t stream) {
  const float* value  = (const float*)d_in[0];
  const float* key_in = (const float*)d_in[1];
  const float* query  = (const float*)d_in[2];
  const int*   pi     = (const int*)d_in[3];
  const float* I_mat  = (const float*)d_in[4];
  const float* ohW    = (const float*)d_in[5];
  const float* ohb    = (const float*)d_in[6];
  const float* Wv     = (const float*)d_in[7];
  const float* Wk     = (const float*)d_in[8];
  const float* Wq     = (const float*)d_in[9];
  const float* Wo     = (const float*)d_in[10];
  const float* bo     = (const float*)d_in[11];
  const float* g1     = (const float*)d_in[12];
  const float* b1     = (const float*)d_in[13];
  const float* g2     = (const float*)d_in[14];
  const float* b2     = (const float*)d_in[15];
  const float* W1     = (const float*)d_in[16];
  const float* bf1    = (const float*)d_in[17];
  const float* W2     = (const float*)d_in[18];
  const float* bf2    = (const float*)d_in[19];

  char* ws = (char*)d_ws;
  const size_t MB = 1024 * 1024;
  unsigned short* q_p  = (unsigned short*)d_out;      // d_out as scratch
  unsigned short* k_p  = q_p + 16777216;
  unsigned short* vP     = (unsigned short*)(ws + 0);        // 32MB, fragment-packed
  unsigned short* attn_o = (unsigned short*)(ws + 32 * MB);  // 32MB
  unsigned short* x_b    = (unsigned short*)(ws + 64 * MB);  // 32MB
  unsigned short* ff1h   = (unsigned short*)(ws + 0);        // 64MB half (aliases vP/attn_o)
  float*          onehot = (float*)(ws + 96 * MB);           // 1MB
  unsigned short* Wv_b   = (unsigned short*)(ws + 97 * MB);
  unsigned short* Wk_b   = Wv_b + 4096;
  unsigned short* Wq_b   = Wk_b + 4096;
  unsigned short* Wop    = Wq_b + 4096;      // 512KB packed
  unsigned short* W1p    = Wop + 262144;     // 2MB packed
  unsigned short* W2p    = W1p + 1048576;    // 2MB packed

  prep_kernel<<<1667, 256, 0, stream>>>(pi, I_mat, ohW, ohb, onehot,
      Wv, Wk, Wq, Wv_b, Wk_b, Wq_b, Wo, W1, W2, Wop, W1p, W2p);

  proj_all<<<12288, 256, 0, stream>>>(value, key_in, query,
      Wv_b, Wk_b, Wq_b, onehot, vP, k_p, q_p);

  attn_kernel<<<2048, 256, 0, stream>>>(q_p, k_p, vP, attn_o);

  // Wo: x_b(bf16) = attn_o @ Wo + bo
  gemmF<false, true, false><<<1024, 256, 0, stream>>>(
      attn_o, 512, Wop, 32, 0, bo, x_b, nullptr, 512, 32768, 512, 4);
  // LN1 in place on x_b, residual = query + onehot
  ln_kernel<true, true, false, true, true><<<8192, 256, 0, stream>>>(
      x_b, query, onehot, g1, b1, x_b);

  // FFN split over 2 row-halves (M=16384 each); FFN2 fuses +x residual
  for (int hf = 0; hf < 2; ++hf) {
    const unsigned short* xh = x_b + (size_t)hf * 16384 * 512;
    gemmF<true, true, false><<<2048, 256, 0, stream>>>(
        xh, 512, W1p, 128, 0, bf1, ff1h, nullptr, 2048, 16384, 512, 16);
    gemmF<false, false, true><<<512, 256, 0, stream>>>(
        ff1h, 2048, W2p, 32, 0, bf2, (float*)d_out + (size_t)hf * 16384 * 512,
        xh, 512, 16384, 2048, 4);
  }
  // LN2: X = d_out f32 (residual already added) -> d_out in place
  ln_kernel<false, false, false, false, false><<<8192, 256, 0, stream>>>(
      d_out, nullptr, nullptr, g2, b2, d_out);
}

// Round 19
// 427.256 us; speedup vs baseline: 1.1577x; 1.0013x over previous
//
#include <hip/hip_runtime.h>

typedef __attribute__((ext_vector_type(8))) short s16x8;
typedef __attribute__((ext_vector_type(4))) float f32x4;

#define TN 288

__device__ __forceinline__ unsigned short f2bf(float f) {
  union { float f; unsigned u; } v; v.f = f;
  unsigned r = v.u + 0x7fffu + ((v.u >> 16) & 1u);
  return (unsigned short)(r >> 16);
}
__device__ __forceinline__ float bf2f(unsigned short u) {
  union { float f; unsigned u; } v; v.u = ((unsigned)u) << 16;
  return v.f;
}
__device__ __forceinline__ unsigned lds_addr(const void* p) {
  return (unsigned)(unsigned long long)(const __attribute__((address_space(3))) char*)p;
}
__device__ __forceinline__ void async_copy16(unsigned short* lds, const unsigned short* g) {
  __builtin_amdgcn_global_load_lds(
      (const __attribute__((address_space(1))) unsigned int*)g,
      (__attribute__((address_space(3))) unsigned int*)lds, 16, 0, 0);
}

// ---------------- fused prep: onehot + weight casts + packs (1 launch) ----
__device__ __forceinline__ void pack_body(const float* __restrict__ W,
    unsigned short* __restrict__ out, int N, long t) {
  int lr = (int)(t & 15);
  int lg = (int)((t >> 4) & 3);
  long g6 = t >> 6;
  int nt = N >> 4;
  int n16 = (int)(g6 % nt);
  int kb = (int)(g6 / nt) << 5;
  int k = kb + lg * 8;
  int col = n16 * 16 + lr;
  s16x8 v;
#pragma unroll
  for (int j = 0; j < 8; ++j) v[j] = (short)f2bf(W[(size_t)(k + j) * N + col]);
  *(s16x8*)(out + t * 8) = v;
}

__global__ __launch_bounds__(256) void prep_kernel(const int* __restrict__ pi,
    const float* __restrict__ I_mat, const float* __restrict__ ohW,
    const float* __restrict__ ohb, float* __restrict__ onehot,
    const float* __restrict__ Wv, const float* __restrict__ Wk,
    const float* __restrict__ Wq, unsigned short* __restrict__ Wv_b,
    unsigned short* __restrict__ Wk_b, unsigned short* __restrict__ Wq_b,
    const float* __restrict__ Wo, const float* __restrict__ W1,
    const float* __restrict__ W2, unsigned short* __restrict__ Wop,
    unsigned short* __restrict__ W1p, unsigned short* __restrict__ W2p) {
  int b = blockIdx.x, tid = threadIdx.x;
  if (b < 512) {
    int t = b;
    int r = (pi[0] + t) % TN;
    float acc0 = ohb[tid], acc1 = ohb[tid + 256];
    const float* Ir = I_mat + (size_t)r * TN;
    for (int j = 0; j < TN; ++j) {
      float iv = Ir[j];
      acc0 += iv * ohW[(size_t)j * 512 + tid];
      acc1 += iv * ohW[(size_t)j * 512 + tid + 256];
    }
    onehot[(size_t)t * 512 + tid] = acc0;
    onehot[(size_t)t * 512 + tid + 256] = acc1;
  } else if (b < 640) {
    pack_body(Wo, Wop, 512, (long)(b - 512) * 256 + tid);
  } else if (b < 1152) {
    pack_body(W1, W1p, 2048, (long)(b - 640) * 256 + tid);
  } else if (b < 1664) {
    pack_body(W2, W2p, 512, (long)(b - 1152) * 256 + tid);
  } else {
    int which = b - 1664;
    const float* src = which == 0 ? Wv : (which == 1 ? Wk : Wq);
    unsigned short* dst = which == 0 ? Wv_b : (which == 1 ? Wk_b : Wq_b);
    float sc = which == 2 ? 0.06375871424f : 1.f;  // Wq: 1/sqrt(512)*log2(e)
#pragma unroll
    for (int j = 0; j < 4; ++j) {
      int i = tid * 16 + j * 4;
      float4 f = *(const float4*)(src + i);
      unsigned lo = (unsigned)f2bf(f.x * sc) | ((unsigned)f2bf(f.y * sc) << 16);
      unsigned hi = (unsigned)f2bf(f.z * sc) | ((unsigned)f2bf(f.w * sc) << 16);
      *(uint2*)(dst + i) = make_uint2(lo, hi);
    }
  }
}

// ---------------- fused projection GEMMs: grid 12288, which = bid>>12 -----
// which 0: V packed into MFMA-fragment order:
//   vP[(n*8+h)*32768 + ((c*16 + ks*4 + fj)*64 + l)*8 + j] =
//     V[t = c*128+ks*32+(l>>4)*8+j][d = fj*16+(l&15)]   (per (n,h))
// which 1: K row-major; which 2: Q (+onehot), row-major
__global__ __launch_bounds__(256) void proj_all(
    const float* __restrict__ value, const float* __restrict__ key_in,
    const float* __restrict__ query, const unsigned short* __restrict__ Wv_b,
    const unsigned short* __restrict__ Wk_b, const unsigned short* __restrict__ Wq_b,
    const float* __restrict__ onehot, unsigned short* __restrict__ vP,
    unsigned short* __restrict__ k_p, unsigned short* __restrict__ q_p) {
  __shared__ unsigned short As[64][40];
  __shared__ unsigned short Bs[64][40];   // Bs[col][k]
  __shared__ unsigned short Cs[64][72];   // V-pack bounce
  const int which = blockIdx.x >> 12;
  const int mb = blockIdx.x & 4095;
  const float* A = which == 0 ? value : (which == 1 ? key_in : query);
  const unsigned short* B = which == 0 ? Wv_b : (which == 1 ? Wk_b : Wq_b);
  unsigned short* C = which == 0 ? vP : (which == 1 ? k_p : q_p);
  const bool qin = (which == 2);
  const int m0 = mb * 64;
  const int tid = threadIdx.x, w = tid >> 6, l = tid & 63, lr = l & 15, lg = l >> 4;
  const int wr = (w >> 1) * 32, wc = (w & 1) * 32;
  const int aRow = (tid * 8) >> 5, aK = (tid * 8) & 31;
  const int bK = (tid * 8) >> 6, bCol = (tid * 8) & 63;
  f32x4 acc[2][2] = {};
  for (int kb = 0; kb < 64; kb += 32) {
    size_t fl = (size_t)(m0 + aRow) * 64 + kb + aK;
    float4 f0 = *(const float4*)(A + fl);
    float4 f1 = *(const float4*)(A + fl + 4);
    if (qin) {
      const float* oh = onehot + (fl & 262143);
      float4 o0 = *(const float4*)(oh);
      float4 o1 = *(const float4*)(oh + 4);
      f0.x += o0.x; f0.y += o0.y; f0.z += o0.z; f0.w += o0.w;
      f1.x += o1.x; f1.y += o1.y; f1.z += o1.z; f1.w += o1.w;
    }
    s16x8 av;
    av[0] = (short)f2bf(f0.x); av[1] = (short)f2bf(f0.y);
    av[2] = (short)f2bf(f0.z); av[3] = (short)f2bf(f0.w);
    av[4] = (short)f2bf(f1.x); av[5] = (short)f2bf(f1.y);
    av[6] = (short)f2bf(f1.z); av[7] = (short)f2bf(f1.w);
    *(s16x8*)&As[aRow][aK] = av;
    s16x8 bv = *(const s16x8*)(B + (size_t)(kb + bK) * 64 + bCol);
#pragma unroll
    for (int j = 0; j < 8; ++j) Bs[bCol + j][bK] = (unsigned short)bv[j];
    __syncthreads();
    s16x8 af0 = *(const s16x8*)&As[wr + lr][lg * 8];
    s16x8 af1 = *(const s16x8*)&As[wr + 16 + lr][lg * 8];
    s16x8 bf0 = *(const s16x8*)&Bs[wc + lr][lg * 8];
    s16x8 bf1 = *(const s16x8*)&Bs[wc + 16 + lr][lg * 8];
    acc[0][0] = __builtin_amdgcn_mfma_f32_16x16x32_bf16(af0, bf0, acc[0][0], 0, 0, 0);
    acc[0][1] = __builtin_amdgcn_mfma_f32_16x16x32_bf16(af0, bf1, acc[0][1], 0, 0, 0);
    acc[1][0] = __builtin_amdgcn_mfma_f32_16x16x32_bf16(af1, bf0, acc[1][0], 0, 0, 0);
    acc[1][1] = __builtin_amdgcn_mfma_f32_16x16x32_bf16(af1, bf1, acc[1][1], 0, 0, 0);
    __syncthreads();
  }
  if (which != 0) {
#pragma unroll
    for (int fi = 0; fi < 2; ++fi)
#pragma unroll
      for (int fj = 0; fj < 2; ++fj)
#pragma unroll
        for (int r = 0; r < 4; ++r) {
          int row = m0 + wr + fi * 16 + lg * 4 + r;
          int col = wc + fj * 16 + lr;
          C[(size_t)row * 64 + col] = f2bf(acc[fi][fj][r]);
        }
  } else {
#pragma unroll
    for (int fi = 0; fi < 2; ++fi)
#pragma unroll
      for (int fj = 0; fj < 2; ++fj)
#pragma unroll
        for (int r = 0; r < 4; ++r)
          Cs[wr + fi * 16 + lg * 4 + r][wc + fj * 16 + lr] = f2bf(acc[fi][fj][r]);
    __syncthreads();
    // rows m0..m0+63 encode (n*512+t)*8+h: t = t0 + r_local/8, h = r_local&7
    int nIdx = m0 >> 12, t0 = (m0 >> 3) & 511;
    int cc = t0 >> 7, ksv = (t0 >> 5) & 3, lgv = (t0 >> 3) & 3;
#pragma unroll
    for (int it = 0; it < 2; ++it) {
      int p = tid + it * 256;
      int hh = p >> 6, d = p & 63;
      s16x8 vv;
#pragma unroll
      for (int j = 0; j < 8; ++j) vv[j] = (short)Cs[j * 8 + hh][d];
      size_t dst = ((size_t)(nIdx * 8 + hh)) * 32768 +
                   (size_t)(((cc * 16 + ksv * 4 + (d >> 4)) * 64) + lgv * 16 + (d & 15)) * 8;
      *(s16x8*)(C + dst) = vv;
    }
  }
}

// ---------------- big GEMM: BK=64, XCD-swizzled 1D grid, B 2-deep prefetch
// RES: add bf16 residual (same ldc) in epilogue
template<bool RELU, bool OUTBF, bool RES>
__global__ __launch_bounds__(256) void gemmF(
    const unsigned short* __restrict__ A, int lda,
    const unsigned short* __restrict__ Bp, int ldbp, int nOff,
    const float* __restrict__ bias, void* __restrict__ Cout,
    const unsigned short* __restrict__ resid, int ldc,
    int M, int K, int nby) {
  __shared__ unsigned short As[2][8192];   // [buf][128 rows x 64 k] src-swizzled
  const int tid = threadIdx.x, w = tid >> 6, l = tid & 63, lr = l & 15, lg = l >> 4;
  const int nwg = gridDim.x;
  const int bid = (blockIdx.x & 7) * (nwg >> 3) + (blockIdx.x >> 3);
  const int bx = bid / nby, by = bid % nby;
  const int m0 = bx * 128;
  const int wr = (w >> 1) * 64, wc = (w & 1) * 64;
  const int srow = tid >> 3, sc8 = tid & 7;
  const int gcol = (sc8 ^ (srow & 7)) * 8;
  const unsigned short* Ag = A + (size_t)(m0 + srow) * lda + gcol;
  const size_t ldaa = (size_t)32 * lda;
  const unsigned short* Bg = Bp +
      ((size_t)(nOff >> 4) + by * 8 + (wc >> 4)) * 512 + lg * 128 + lr * 8;
  const size_t bks = (size_t)ldbp * 512;

  f32x4 acc[4][4] = {};
  s16x8 b0[4], b1[4];

#pragma unroll
  for (int it = 0; it < 4; ++it)
    async_copy16(&As[0][(it * 256 + tid) * 8], Ag + it * ldaa);
#pragma unroll
  for (int fj = 0; fj < 4; ++fj) {
    b0[fj] = *(const s16x8*)(Bg + fj * 512);
    b1[fj] = *(const s16x8*)(Bg + bks + fj * 512);
  }
  __syncthreads();

  int buf = 0;
  for (int kb = 0; kb < K; kb += 64) {
    int kn = (kb + 64 < K) ? kb + 64 : 0;
#pragma unroll
    for (int it = 0; it < 4; ++it)
      async_copy16(&As[buf ^ 1][(it * 256 + tid) * 8], Ag + kn + it * ldaa);
    s16x8 b0n[4];
    {
      const unsigned short* p = Bg + ((size_t)(kn >> 5)) * bks;
#pragma unroll
      for (int fj = 0; fj < 4; ++fj) b0n[fj] = *(const s16x8*)(p + fj * 512);
    }
    {
      s16x8 af[4];
#pragma unroll
      for (int fi = 0; fi < 4; ++fi) {
        int row = wr + fi * 16 + lr;
        af[fi] = *(const s16x8*)&As[buf][row * 64 + ((lg ^ (row & 7)) * 8)];
      }
#pragma unroll
      for (int fi = 0; fi < 4; ++fi)
#pragma unroll
        for (int fj = 0; fj < 4; ++fj)
          acc[fi][fj] = __builtin_amdgcn_mfma_f32_16x16x32_bf16(af[fi], b0[fj], acc[fi][fj], 0, 0, 0);
    }
    s16x8 b1n[4];
    {
      const unsigned short* p = Bg + ((size_t)((kn + 32) >> 5)) * bks;
#pragma unroll
      for (int fj = 0; fj < 4; ++fj) b1n[fj] = *(const s16x8*)(p + fj * 512);
    }
    {
      s16x8 af[4];
#pragma unroll
      for (int fi = 0; fi < 4; ++fi) {
        int row = wr + fi * 16 + lr;
        af[fi] = *(const s16x8*)&As[buf][row * 64 + (((4 + lg) ^ (row & 7)) * 8)];
      }
#pragma unroll
      for (int fi = 0; fi < 4; ++fi)
#pragma unroll
        for (int fj = 0; fj < 4; ++fj)
          acc[fi][fj] = __builtin_amdgcn_mfma_f32_16x16x32_bf16(af[fi], b1[fj], acc[fi][fj], 0, 0, 0);
    }
    __syncthreads();
#pragma unroll
    for (int fj = 0; fj < 4; ++fj) { b0[fj] = b0n[fj]; b1[fj] = b1n[fj]; }
    buf ^= 1;
  }

#pragma unroll
  for (int fj = 0; fj < 4; ++fj) {
    int colL = by * 128 + wc + fj * 16 + lr;
    float bv = bias[nOff + colL];
#pragma unroll
    for (int fi = 0; fi < 4; ++fi)
#pragma unroll
      for (int r = 0; r < 4; ++r) {
        int row = m0 + wr + fi * 16 + lg * 4 + r;
        size_t ci = (size_t)row * ldc + colL;
        float v = acc[fi][fj][r] + bv;
        if (RES) v += bf2f(resid[ci]);
        if (RELU) v = fmaxf(v, 0.f);
        if (OUTBF) ((unsigned short*)Cout)[ci] = f2bf(v);
        else ((float*)Cout)[ci] = v;
      }
  }
}

// ---------------- flash attention (R18 + KS double-buffer, 1 barrier/chunk)
// grid 2048; chunked XCD remap (FETCH 147->49MB). Q in regs; K staged in a
// DOUBLE-BUFFERED LDS tile: next chunk's K loaded to kreg at compute top
// (T14 issue-early), written to KS[cur^1] at compute end (no hazard: readers
// use KS[cur]), ONE barrier per chunk flips. Pad 72->68 keeps reads
// conflict-free and drops LDS to 51.7KB -> 3 blocks/CU. V fragment-packed,
// loaded at compute top; exp2-unit softmax.
__global__ __launch_bounds__(256, 2) void attn_kernel(
    const unsigned short* __restrict__ Qp, const unsigned short* __restrict__ Kp,
    const unsigned short* __restrict__ Vt, unsigned short* __restrict__ Out) {
  __shared__ unsigned short KS[2][128][68];
  __shared__ unsigned short P[4][16][132];
  const int orig = (blockIdx.x & 7) * 256 + (blockIdx.x >> 3);
  const int qq = orig & 3, g = orig >> 2, h = g & 7, n = g >> 3;
  const int tid = threadIdx.x, w = tid >> 6, l = tid & 63, lr = l & 15, lg = l >> 4;
  const int q0 = qq * 128;

  s16x8 qf[2][2];
#pragma unroll
  for (int rt = 0; rt < 2; ++rt) {
    const size_t qb = (((size_t)(n * 512 + q0 + w * 32 + rt * 16 + lr)) * 8 + h) * 64;
    qf[rt][0] = *(const s16x8*)(Qp + qb + lg * 8);
    qf[rt][1] = *(const s16x8*)(Qp + qb + 32 + lg * 8);
  }
  const unsigned short* Vfb = Vt + ((size_t)(n * 8 + h)) * 32768 + (size_t)l * 8;
  const int srr = tid >> 3, sdd = (tid & 7) * 8;   // staging slot (it stride 32 rows)

  f32x4 oacc[2][4] = {};
  float m[2][4], lsum[2][4];
#pragma unroll
  for (int rt = 0; rt < 2; ++rt)
#pragma unroll
    for (int r = 0; r < 4; ++r) { m[rt][r] = -1e30f; lsum[rt][r] = 0.f; }
  s16x8 vreg[16], kreg[4];

  // prologue: stage K(0) direct into KS[0]
#pragma unroll
  for (int it = 0; it < 4; ++it)
    *(s16x8*)&KS[0][it * 32 + srr][sdd] =
        *(const s16x8*)(Kp + (((size_t)(n * 512 + it * 32 + srr)) * 8 + h) * 64 + sdd);
  __syncthreads();

  int cur = 0;
  for (int c = 0; c < 4; ++c) {
    // issue-early: next chunk's K into registers (latency hides under compute)
    if (c < 3) {
#pragma unroll
      for (int it = 0; it < 4; ++it)
        kreg[it] = *(const s16x8*)(
            Kp + (((size_t)(n * 512 + (c + 1) * 128 + it * 32 + srr)) * 8 + h) * 64 + sdd);
    }
    // V(c) loads: first PV use is after QK^T+softmax (~700cy) — covered
#pragma unroll
    for (int i = 0; i < 16; ++i)
      vreg[i] = *(const s16x8*)(Vfb + ((size_t)(c * 16 + i) << 9));

#pragma unroll
    for (int rt = 0; rt < 2; ++rt) {
      f32x4 sacc[8];
      __builtin_amdgcn_s_setprio(1);
#pragma unroll
      for (int f = 0; f < 8; ++f) {
        s16x8 b0 = *(const s16x8*)&KS[cur][f * 16 + lr][lg * 8];
        s16x8 b1 = *(const s16x8*)&KS[cur][f * 16 + lr][32 + lg * 8];
        f32x4 a = {};
        a = __builtin_amdgcn_mfma_f32_16x16x32_bf16(qf[rt][0], b0, a, 0, 0, 0);
        a = __builtin_amdgcn_mfma_f32_16x16x32_bf16(qf[rt][1], b1, a, 0, 0, 0);
        sacc[f] = a;
      }
      __builtin_amdgcn_s_setprio(0);

      float fs[4];
#pragma unroll
      for (int r = 0; r < 4; ++r) {
        float cm = sacc[0][r];
#pragma unroll
        for (int f = 1; f < 8; ++f) cm = fmaxf(cm, sacc[f][r]);
#pragma unroll
        for (int mk = 1; mk < 16; mk <<= 1) cm = fmaxf(cm, __shfl_xor(cm, mk));
        float mn = fmaxf(m[rt][r], cm);
        fs[r] = __builtin_amdgcn_exp2f(m[rt][r] - mn);   // exp2 units
        m[rt][r] = mn;
        unsigned pa = lds_addr(&P[w][lg * 4 + r][lr]);
        float cs = 0.f;
#pragma unroll
        for (int f = 0; f < 8; ++f) {
          float p = __builtin_amdgcn_exp2f(sacc[f][r] - mn);
          asm volatile("ds_write_b16_d16_hi %0, %1 offset:%2"
                       :: "v"(pa), "v"(p), "i"(f * 32) : "memory");
          cs += p;
        }
#pragma unroll
        for (int mk = 1; mk < 16; mk <<= 1) cs += __shfl_xor(cs, mk);
        lsum[rt][r] = lsum[rt][r] * fs[r] + cs;
      }
#pragma unroll
      for (int fj = 0; fj < 4; ++fj)
#pragma unroll
        for (int r = 0; r < 4; ++r) oacc[rt][fj][r] *= fs[r];

      asm volatile("s_waitcnt lgkmcnt(0)" ::: "memory");
      __builtin_amdgcn_sched_barrier(0);
      __builtin_amdgcn_s_setprio(1);
#pragma unroll
      for (int ks = 0; ks < 4; ++ks) {
        s16x8 pa = *(const s16x8*)&P[w][lr][ks * 32 + lg * 8];
#pragma unroll
        for (int fj = 0; fj < 4; ++fj)
          oacc[rt][fj] = __builtin_amdgcn_mfma_f32_16x16x32_bf16(pa, vreg[ks * 4 + fj], oacc[rt][fj], 0, 0, 0);
      }
      __builtin_amdgcn_s_setprio(0);
    }

    if (c < 3) {
      // write to the INACTIVE buffer (no hazard; no barrier needed before)
#pragma unroll
      for (int it = 0; it < 4; ++it)
        *(s16x8*)&KS[cur ^ 1][it * 32 + srr][sdd] = kreg[it];
      __syncthreads();   // one barrier: writes visible + all reads of KS[cur] done
      cur ^= 1;
    }
  }

#pragma unroll
  for (int rt = 0; rt < 2; ++rt)
#pragma unroll
    for (int fj = 0; fj < 4; ++fj)
#pragma unroll
      for (int r = 0; r < 4; ++r) {
        int qrow = q0 + w * 32 + rt * 16 + lg * 4 + r;
        Out[((size_t)(n * 512 + qrow)) * 512 + h * 64 + fj * 16 + lr] =
            f2bf(oacc[rt][fj][r] / lsum[rt][r]);
      }
}

// ---------------- layernorm: 1 wave per 512-elem row, fused residual ------
// RES: add residual R (RBF selects bf16/f32); QIN: add onehot row
template<bool XBF, bool RES, bool RBF, bool QIN, bool OUTBF>
__global__ __launch_bounds__(256) void ln_kernel(const void* __restrict__ Xv,
    const void* __restrict__ Rv, const float* __restrict__ onehot,
    const float* __restrict__ g, const float* __restrict__ bb,
    void* __restrict__ outv) {
  int row = blockIdx.x * 4 + (threadIdx.x >> 6);
  int l = threadIdx.x & 63;
  size_t base = (size_t)row * 512 + l * 8;
  float v[8];
  if (XBF) {
    s16x8 xv = *(const s16x8*)((const unsigned short*)Xv + base);
#pragma unroll
    for (int j = 0; j < 8; ++j) v[j] = bf2f((unsigned short)xv[j]);
  } else {
    const float* X = (const float*)Xv;
    float4 x0 = *(const float4*)(X + base);
    float4 x1 = *(const float4*)(X + base + 4);
    v[0] = x0.x; v[1] = x0.y; v[2] = x0.z; v[3] = x0.w;
    v[4] = x1.x; v[5] = x1.y; v[6] = x1.z; v[7] = x1.w;
  }
  if (RES) {
    if (RBF) {
      s16x8 rv = *(const s16x8*)((const unsigned short*)Rv + base);
#pragma unroll
      for (int j = 0; j < 8; ++j) v[j] += bf2f((unsigned short)rv[j]);
    } else {
      const float* R = (const float*)Rv;
      float4 r0 = *(const float4*)(R + base);
      float4 r1 = *(const float4*)(R + base + 4);
      v[0] += r0.x; v[1] += r0.y; v[2] += r0.z; v[3] += r0.w;
      v[4] += r1.x; v[5] += r1.y; v[6] += r1.z; v[7] += r1.w;
    }
  }
  if (QIN) {
    size_t ob = (size_t)(row & 511) * 512 + l * 8;
    float4 o0 = *(const float4*)(onehot + ob);
    float4 o1 = *(const float4*)(onehot + ob + 4);
    v[0] += o0.x; v[1] += o0.y; v[2] += o0.z; v[3] += o0.w;
    v[4] += o1.x; v[5] += o1.y; v[6] += o1.z; v[7] += o1.w;
  }
  float s = 0.f, ss = 0.f;
#pragma unroll
  for (int j = 0; j < 8; ++j) { s += v[j]; ss += v[j] * v[j]; }
#pragma unroll
  for (int mk = 1; mk < 64; mk <<= 1) { s += __shfl_xor(s, mk); ss += __shfl_xor(ss, mk); }
  float mu = s * (1.f / 512.f);
  float inv = rsqrtf(ss * (1.f / 512.f) - mu * mu + 1e-5f);
#pragma unroll
  for (int j = 0; j < 8; ++j) {
    int e = l * 8 + j;
    float y = (v[j] - mu) * inv * g[e] + bb[e];
    if (OUTBF) ((unsigned short*)outv)[base + j] = f2bf(y);
    else ((float*)outv)[base + j] = y;
  }
}

extern "C" void kernel_launch(void* const* d_in, const int* in_sizes, int n_in,
                              void* d_out, int out_size, void* d_ws, size_t ws_size,
                              hipStream_t stream) {
  const float* value  = (const float*)d_in[0];
  const float* key_in = (const float*)d_in[1];
  const float* query  = (const float*)d_in[2];
  const int*   pi     = (const int*)d_in[3];
  const float* I_mat  = (const float*)d_in[4];
  const float* ohW    = (const float*)d_in[5];
  const float* ohb    = (const float*)d_in[6];
  const float* Wv     = (const float*)d_in[7];
  const float* Wk     = (const float*)d_in[8];
  const float* Wq     = (const float*)d_in[9];
  const float* Wo     = (const float*)d_in[10];
  const float* bo     = (const float*)d_in[11];
  const float* g1     = (const float*)d_in[12];
  const float* b1     = (const float*)d_in[13];
  const float* g2     = (const float*)d_in[14];
  const float* b2     = (const float*)d_in[15];
  const float* W1     = (const float*)d_in[16];
  const float* bf1    = (const float*)d_in[17];
  const float* W2     = (const float*)d_in[18];
  const float* bf2    = (const float*)d_in[19];

  char* ws = (char*)d_ws;
  const size_t MB = 1024 * 1024;
  unsigned short* q_p  = (unsigned short*)d_out;      // d_out as scratch
  unsigned short* k_p  = q_p + 16777216;
  unsigned short* vP     = (unsigned short*)(ws + 0);        // 32MB, fragment-packed
  unsigned short* attn_o = (unsigned short*)(ws + 32 * MB);  // 32MB
  unsigned short* x_b    = (unsigned short*)(ws + 64 * MB);  // 32MB
  unsigned short* ff1h   = (unsigned short*)(ws + 0);        // 64MB half (aliases vP/attn_o)
  float*          onehot = (float*)(ws + 96 * MB);           // 1MB
  unsigned short* Wv_b   = (unsigned short*)(ws + 97 * MB);
  unsigned short* Wk_b   = Wv_b + 4096;
  unsigned short* Wq_b   = Wk_b + 4096;
  unsigned short* Wop    = Wq_b + 4096;      // 512KB packed
  unsigned short* W1p    = Wop + 262144;     // 2MB packed
  unsigned short* W2p    = W1p + 1048576;    // 2MB packed

  prep_kernel<<<1667, 256, 0, stream>>>(pi, I_mat, ohW, ohb, onehot,
      Wv, Wk, Wq, Wv_b, Wk_b, Wq_b, Wo, W1, W2, Wop, W1p, W2p);

  proj_all<<<12288, 256, 0, stream>>>(value, key_in, query,
      Wv_b, Wk_b, Wq_b, onehot, vP, k_p, q_p);

  attn_kernel<<<2048, 256, 0, stream>>>(q_p, k_p, vP, attn_o);

  // Wo: x_b(bf16) = attn_o @ Wo + bo
  gemmF<false, true, false><<<1024, 256, 0, stream>>>(
      attn_o, 512, Wop, 32, 0, bo, x_b, nullptr, 512, 32768, 512, 4);
  // LN1 in place on x_b, residual = query + onehot
  ln_kernel<true, true, false, true, true><<<8192, 256, 0, stream>>>(
      x_b, query, onehot, g1, b1, x_b);

  // FFN split over 2 row-halves (M=16384 each); FFN2 fuses +x residual
  for (int hf = 0; hf < 2; ++hf) {
    const unsigned short* xh = x_b + (size_t)hf * 16384 * 512;
    gemmF<true, true, false><<<2048, 256, 0, stream>>>(
        xh, 512, W1p, 128, 0, bf1, ff1h, nullptr, 2048, 16384, 512, 16);
    gemmF<false, false, true><<<512, 256, 0, stream>>>(
        ff1h, 2048, W2p, 32, 0, bf2, (float*)d_out + (size_t)hf * 16384 * 512,
        xh, 512, 16384, 2048, 4);
  }
  // LN2: X = d_out f32 (residual already added) -> d_out in place
  ln_kernel<false, false, false, false, false><<<8192, 256, 0, stream>>>(
      d_out, nullptr, nullptr, g2, b2, d_out);
}

// Round 20
// 426.706 us; speedup vs baseline: 1.1592x; 1.0013x over previous
//
#include <hip/hip_runtime.h>

typedef __attribute__((ext_vector_type(8))) short s16x8;
typedef __attribute__((ext_vector_type(4))) float f32x4;

#define TN 288

__device__ __forceinline__ unsigned short f2bf(float f) {
  union { float f; unsigned u; } v; v.f = f;
  unsigned r = v.u + 0x7fffu + ((v.u >> 16) & 1u);
  return (unsigned short)(r >> 16);
}
__device__ __forceinline__ float bf2f(unsigned short u) {
  union { float f; unsigned u; } v; v.u = ((unsigned)u) << 16;
  return v.f;
}
__device__ __forceinline__ unsigned lds_addr(const void* p) {
  return (unsigned)(unsigned long long)(const __attribute__((address_space(3))) char*)p;
}
__device__ __forceinline__ void async_copy16(unsigned short* lds, const unsigned short* g) {
  __builtin_amdgcn_global_load_lds(
      (const __attribute__((address_space(1))) unsigned int*)g,
      (__attribute__((address_space(3))) unsigned int*)lds, 16, 0, 0);
}

// ---------------- fused prep: onehot + weight casts + packs (1 launch) ----
__device__ __forceinline__ void pack_body(const float* __restrict__ W,
    unsigned short* __restrict__ out, int N, long t) {
  int lr = (int)(t & 15);
  int lg = (int)((t >> 4) & 3);
  long g6 = t >> 6;
  int nt = N >> 4;
  int n16 = (int)(g6 % nt);
  int kb = (int)(g6 / nt) << 5;
  int k = kb + lg * 8;
  int col = n16 * 16 + lr;
  s16x8 v;
#pragma unroll
  for (int j = 0; j < 8; ++j) v[j] = (short)f2bf(W[(size_t)(k + j) * N + col]);
  *(s16x8*)(out + t * 8) = v;
}

__global__ __launch_bounds__(256) void prep_kernel(const int* __restrict__ pi,
    const float* __restrict__ I_mat, const float* __restrict__ ohW,
    const float* __restrict__ ohb, float* __restrict__ onehot,
    const float* __restrict__ Wv, const float* __restrict__ Wk,
    const float* __restrict__ Wq, unsigned short* __restrict__ Wv_b,
    unsigned short* __restrict__ Wk_b, unsigned short* __restrict__ Wq_b,
    const float* __restrict__ Wo, const float* __restrict__ W1,
    const float* __restrict__ W2, unsigned short* __restrict__ Wop,
    unsigned short* __restrict__ W1p, unsigned short* __restrict__ W2p) {
  int b = blockIdx.x, tid = threadIdx.x;
  if (b < 512) {
    int t = b;
    int r = (pi[0] + t) % TN;
    float acc0 = ohb[tid], acc1 = ohb[tid + 256];
    const float* Ir = I_mat + (size_t)r * TN;
    for (int j = 0; j < TN; ++j) {
      float iv = Ir[j];
      acc0 += iv * ohW[(size_t)j * 512 + tid];
      acc1 += iv * ohW[(size_t)j * 512 + tid + 256];
    }
    onehot[(size_t)t * 512 + tid] = acc0;
    onehot[(size_t)t * 512 + tid + 256] = acc1;
  } else if (b < 640) {
    pack_body(Wo, Wop, 512, (long)(b - 512) * 256 + tid);
  } else if (b < 1152) {
    pack_body(W1, W1p, 2048, (long)(b - 640) * 256 + tid);
  } else if (b < 1664) {
    pack_body(W2, W2p, 512, (long)(b - 1152) * 256 + tid);
  } else {
    int which = b - 1664;
    const float* src = which == 0 ? Wv : (which == 1 ? Wk : Wq);
    unsigned short* dst = which == 0 ? Wv_b : (which == 1 ? Wk_b : Wq_b);
    float sc = which == 2 ? 0.06375871424f : 1.f;  // Wq: 1/sqrt(512)*log2(e)
#pragma unroll
    for (int j = 0; j < 4; ++j) {
      int i = tid * 16 + j * 4;
      float4 f = *(const float4*)(src + i);
      unsigned lo = (unsigned)f2bf(f.x * sc) | ((unsigned)f2bf(f.y * sc) << 16);
      unsigned hi = (unsigned)f2bf(f.z * sc) | ((unsigned)f2bf(f.w * sc) << 16);
      *(uint2*)(dst + i) = make_uint2(lo, hi);
    }
  }
}

// ---------------- fused projection GEMMs: grid 12288, which = bid>>12 -----
// which 0: V packed into MFMA-fragment order:
//   vP[(n*8+h)*32768 + ((c*16 + ks*4 + fj)*64 + l)*8 + j] =
//     V[t = c*128+ks*32+(l>>4)*8+j][d = fj*16+(l&15)]   (per (n,h))
// which 1: K row-major; which 2: Q (+onehot), row-major
__global__ __launch_bounds__(256) void proj_all(
    const float* __restrict__ value, const float* __restrict__ key_in,
    const float* __restrict__ query, const unsigned short* __restrict__ Wv_b,
    const unsigned short* __restrict__ Wk_b, const unsigned short* __restrict__ Wq_b,
    const float* __restrict__ onehot, unsigned short* __restrict__ vP,
    unsigned short* __restrict__ k_p, unsigned short* __restrict__ q_p) {
  __shared__ unsigned short As[64][40];
  __shared__ unsigned short Bs[64][40];   // Bs[col][k]
  __shared__ unsigned short Cs[64][72];   // V-pack bounce
  const int which = blockIdx.x >> 12;
  const int mb = blockIdx.x & 4095;
  const float* A = which == 0 ? value : (which == 1 ? key_in : query);
  const unsigned short* B = which == 0 ? Wv_b : (which == 1 ? Wk_b : Wq_b);
  unsigned short* C = which == 0 ? vP : (which == 1 ? k_p : q_p);
  const bool qin = (which == 2);
  const int m0 = mb * 64;
  const int tid = threadIdx.x, w = tid >> 6, l = tid & 63, lr = l & 15, lg = l >> 4;
  const int wr = (w >> 1) * 32, wc = (w & 1) * 32;
  const int aRow = (tid * 8) >> 5, aK = (tid * 8) & 31;
  const int bK = (tid * 8) >> 6, bCol = (tid * 8) & 63;
  f32x4 acc[2][2] = {};
  for (int kb = 0; kb < 64; kb += 32) {
    size_t fl = (size_t)(m0 + aRow) * 64 + kb + aK;
    float4 f0 = *(const float4*)(A + fl);
    float4 f1 = *(const float4*)(A + fl + 4);
    if (qin) {
      const float* oh = onehot + (fl & 262143);
      float4 o0 = *(const float4*)(oh);
      float4 o1 = *(const float4*)(oh + 4);
      f0.x += o0.x; f0.y += o0.y; f0.z += o0.z; f0.w += o0.w;
      f1.x += o1.x; f1.y += o1.y; f1.z += o1.z; f1.w += o1.w;
    }
    s16x8 av;
    av[0] = (short)f2bf(f0.x); av[1] = (short)f2bf(f0.y);
    av[2] = (short)f2bf(f0.z); av[3] = (short)f2bf(f0.w);
    av[4] = (short)f2bf(f1.x); av[5] = (short)f2bf(f1.y);
    av[6] = (short)f2bf(f1.z); av[7] = (short)f2bf(f1.w);
    *(s16x8*)&As[aRow][aK] = av;
    s16x8 bv = *(const s16x8*)(B + (size_t)(kb + bK) * 64 + bCol);
#pragma unroll
    for (int j = 0; j < 8; ++j) Bs[bCol + j][bK] = (unsigned short)bv[j];
    __syncthreads();
    s16x8 af0 = *(const s16x8*)&As[wr + lr][lg * 8];
    s16x8 af1 = *(const s16x8*)&As[wr + 16 + lr][lg * 8];
    s16x8 bf0 = *(const s16x8*)&Bs[wc + lr][lg * 8];
    s16x8 bf1 = *(const s16x8*)&Bs[wc + 16 + lr][lg * 8];
    acc[0][0] = __builtin_amdgcn_mfma_f32_16x16x32_bf16(af0, bf0, acc[0][0], 0, 0, 0);
    acc[0][1] = __builtin_amdgcn_mfma_f32_16x16x32_bf16(af0, bf1, acc[0][1], 0, 0, 0);
    acc[1][0] = __builtin_amdgcn_mfma_f32_16x16x32_bf16(af1, bf0, acc[1][0], 0, 0, 0);
    acc[1][1] = __builtin_amdgcn_mfma_f32_16x16x32_bf16(af1, bf1, acc[1][1], 0, 0, 0);
    __syncthreads();
  }
  if (which != 0) {
#pragma unroll
    for (int fi = 0; fi < 2; ++fi)
#pragma unroll
      for (int fj = 0; fj < 2; ++fj)
#pragma unroll
        for (int r = 0; r < 4; ++r) {
          int row = m0 + wr + fi * 16 + lg * 4 + r;
          int col = wc + fj * 16 + lr;
          C[(size_t)row * 64 + col] = f2bf(acc[fi][fj][r]);
        }
  } else {
#pragma unroll
    for (int fi = 0; fi < 2; ++fi)
#pragma unroll
      for (int fj = 0; fj < 2; ++fj)
#pragma unroll
        for (int r = 0; r < 4; ++r)
          Cs[wr + fi * 16 + lg * 4 + r][wc + fj * 16 + lr] = f2bf(acc[fi][fj][r]);
    __syncthreads();
    // rows m0..m0+63 encode (n*512+t)*8+h: t = t0 + r_local/8, h = r_local&7
    int nIdx = m0 >> 12, t0 = (m0 >> 3) & 511;
    int cc = t0 >> 7, ksv = (t0 >> 5) & 3, lgv = (t0 >> 3) & 3;
#pragma unroll
    for (int it = 0; it < 2; ++it) {
      int p = tid + it * 256;
      int hh = p >> 6, d = p & 63;
      s16x8 vv;
#pragma unroll
      for (int j = 0; j < 8; ++j) vv[j] = (short)Cs[j * 8 + hh][d];
      size_t dst = ((size_t)(nIdx * 8 + hh)) * 32768 +
                   (size_t)(((cc * 16 + ksv * 4 + (d >> 4)) * 64) + lgv * 16 + (d & 15)) * 8;
      *(s16x8*)(C + dst) = vv;
    }
  }
}

// ---------------- big GEMM: BK=64, XCD-swizzled 1D grid, B 2-deep prefetch
// RES: add bf16 residual (same ldc) in epilogue
template<bool RELU, bool OUTBF, bool RES>
__global__ __launch_bounds__(256) void gemmF(
    const unsigned short* __restrict__ A, int lda,
    const unsigned short* __restrict__ Bp, int ldbp, int nOff,
    const float* __restrict__ bias, void* __restrict__ Cout,
    const unsigned short* __restrict__ resid, int ldc,
    int M, int K, int nby) {
  __shared__ unsigned short As[2][8192];   // [buf][128 rows x 64 k] src-swizzled
  const int tid = threadIdx.x, w = tid >> 6, l = tid & 63, lr = l & 15, lg = l >> 4;
  const int nwg = gridDim.x;
  const int bid = (blockIdx.x & 7) * (nwg >> 3) + (blockIdx.x >> 3);
  const int bx = bid / nby, by = bid % nby;
  const int m0 = bx * 128;
  const int wr = (w >> 1) * 64, wc = (w & 1) * 64;
  const int srow = tid >> 3, sc8 = tid & 7;
  const int gcol = (sc8 ^ (srow & 7)) * 8;
  const unsigned short* Ag = A + (size_t)(m0 + srow) * lda + gcol;
  const size_t ldaa = (size_t)32 * lda;
  const unsigned short* Bg = Bp +
      ((size_t)(nOff >> 4) + by * 8 + (wc >> 4)) * 512 + lg * 128 + lr * 8;
  const size_t bks = (size_t)ldbp * 512;

  f32x4 acc[4][4] = {};
  s16x8 b0[4], b1[4];

#pragma unroll
  for (int it = 0; it < 4; ++it)
    async_copy16(&As[0][(it * 256 + tid) * 8], Ag + it * ldaa);
#pragma unroll
  for (int fj = 0; fj < 4; ++fj) {
    b0[fj] = *(const s16x8*)(Bg + fj * 512);
    b1[fj] = *(const s16x8*)(Bg + bks + fj * 512);
  }
  __syncthreads();

  int buf = 0;
  for (int kb = 0; kb < K; kb += 64) {
    int kn = (kb + 64 < K) ? kb + 64 : 0;
#pragma unroll
    for (int it = 0; it < 4; ++it)
      async_copy16(&As[buf ^ 1][(it * 256 + tid) * 8], Ag + kn + it * ldaa);
    s16x8 b0n[4];
    {
      const unsigned short* p = Bg + ((size_t)(kn >> 5)) * bks;
#pragma unroll
      for (int fj = 0; fj < 4; ++fj) b0n[fj] = *(const s16x8*)(p + fj * 512);
    }
    {
      s16x8 af[4];
#pragma unroll
      for (int fi = 0; fi < 4; ++fi) {
        int row = wr + fi * 16 + lr;
        af[fi] = *(const s16x8*)&As[buf][row * 64 + ((lg ^ (row & 7)) * 8)];
      }
#pragma unroll
      for (int fi = 0; fi < 4; ++fi)
#pragma unroll
        for (int fj = 0; fj < 4; ++fj)
          acc[fi][fj] = __builtin_amdgcn_mfma_f32_16x16x32_bf16(af[fi], b0[fj], acc[fi][fj], 0, 0, 0);
    }
    s16x8 b1n[4];
    {
      const unsigned short* p = Bg + ((size_t)((kn + 32) >> 5)) * bks;
#pragma unroll
      for (int fj = 0; fj < 4; ++fj) b1n[fj] = *(const s16x8*)(p + fj * 512);
    }
    {
      s16x8 af[4];
#pragma unroll
      for (int fi = 0; fi < 4; ++fi) {
        int row = wr + fi * 16 + lr;
        af[fi] = *(const s16x8*)&As[buf][row * 64 + (((4 + lg) ^ (row & 7)) * 8)];
      }
#pragma unroll
      for (int fi = 0; fi < 4; ++fi)
#pragma unroll
        for (int fj = 0; fj < 4; ++fj)
          acc[fi][fj] = __builtin_amdgcn_mfma_f32_16x16x32_bf16(af[fi], b1[fj], acc[fi][fj], 0, 0, 0);
    }
    __syncthreads();
#pragma unroll
    for (int fj = 0; fj < 4; ++fj) { b0[fj] = b0n[fj]; b1[fj] = b1n[fj]; }
    buf ^= 1;
  }

#pragma unroll
  for (int fj = 0; fj < 4; ++fj) {
    int colL = by * 128 + wc + fj * 16 + lr;
    float bv = bias[nOff + colL];
#pragma unroll
    for (int fi = 0; fi < 4; ++fi)
#pragma unroll
      for (int r = 0; r < 4; ++r) {
        int row = m0 + wr + fi * 16 + lg * 4 + r;
        size_t ci = (size_t)row * ldc + colL;
        float v = acc[fi][fj][r] + bv;
        if (RES) v += bf2f(resid[ci]);
        if (RELU) v = fmaxf(v, 0.f);
        if (OUTBF) ((unsigned short*)Cout)[ci] = f2bf(v);
        else ((float*)Cout)[ci] = v;
      }
  }
}

// ---------------- flash attention (final: R18 + KS double-buffer) ---------
// grid 2048; chunked XCD remap (FETCH 147->49MB). Q in regs; K staged in a
// DOUBLE-BUFFERED LDS tile: next chunk's K loaded to kreg at compute top
// (T14 issue-early), written to KS[cur^1] at compute end (no hazard: readers
// use KS[cur]), ONE barrier per chunk flips. V fragment-packed, loaded at
// compute top; exp2-unit softmax. Bank conflicts: 0 (measured R19).
__global__ __launch_bounds__(256, 2) void attn_kernel(
    const unsigned short* __restrict__ Qp, const unsigned short* __restrict__ Kp,
    const unsigned short* __restrict__ Vt, unsigned short* __restrict__ Out) {
  __shared__ unsigned short KS[2][128][68];
  __shared__ unsigned short P[4][16][132];
  const int orig = (blockIdx.x & 7) * 256 + (blockIdx.x >> 3);
  const int qq = orig & 3, g = orig >> 2, h = g & 7, n = g >> 3;
  const int tid = threadIdx.x, w = tid >> 6, l = tid & 63, lr = l & 15, lg = l >> 4;
  const int q0 = qq * 128;

  s16x8 qf[2][2];
#pragma unroll
  for (int rt = 0; rt < 2; ++rt) {
    const size_t qb = (((size_t)(n * 512 + q0 + w * 32 + rt * 16 + lr)) * 8 + h) * 64;
    qf[rt][0] = *(const s16x8*)(Qp + qb + lg * 8);
    qf[rt][1] = *(const s16x8*)(Qp + qb + 32 + lg * 8);
  }
  const unsigned short* Vfb = Vt + ((size_t)(n * 8 + h)) * 32768 + (size_t)l * 8;
  const int srr = tid >> 3, sdd = (tid & 7) * 8;   // staging slot (it stride 32 rows)

  f32x4 oacc[2][4] = {};
  float m[2][4], lsum[2][4];
#pragma unroll
  for (int rt = 0; rt < 2; ++rt)
#pragma unroll
    for (int r = 0; r < 4; ++r) { m[rt][r] = -1e30f; lsum[rt][r] = 0.f; }
  s16x8 vreg[16], kreg[4];

  // prologue: stage K(0) direct into KS[0]
#pragma unroll
  for (int it = 0; it < 4; ++it)
    *(s16x8*)&KS[0][it * 32 + srr][sdd] =
        *(const s16x8*)(Kp + (((size_t)(n * 512 + it * 32 + srr)) * 8 + h) * 64 + sdd);
  __syncthreads();

  int cur = 0;
  for (int c = 0; c < 4; ++c) {
    // issue-early: next chunk's K into registers (latency hides under compute)
    if (c < 3) {
#pragma unroll
      for (int it = 0; it < 4; ++it)
        kreg[it] = *(const s16x8*)(
            Kp + (((size_t)(n * 512 + (c + 1) * 128 + it * 32 + srr)) * 8 + h) * 64 + sdd);
    }
    // V(c) loads: first PV use is after QK^T+softmax (~700cy) — covered
#pragma unroll
    for (int i = 0; i < 16; ++i)
      vreg[i] = *(const s16x8*)(Vfb + ((size_t)(c * 16 + i) << 9));

#pragma unroll
    for (int rt = 0; rt < 2; ++rt) {
      f32x4 sacc[8];
      __builtin_amdgcn_s_setprio(1);
#pragma unroll
      for (int f = 0; f < 8; ++f) {
        s16x8 b0 = *(const s16x8*)&KS[cur][f * 16 + lr][lg * 8];
        s16x8 b1 = *(const s16x8*)&KS[cur][f * 16 + lr][32 + lg * 8];
        f32x4 a = {};
        a = __builtin_amdgcn_mfma_f32_16x16x32_bf16(qf[rt][0], b0, a, 0, 0, 0);
        a = __builtin_amdgcn_mfma_f32_16x16x32_bf16(qf[rt][1], b1, a, 0, 0, 0);
        sacc[f] = a;
      }
      __builtin_amdgcn_s_setprio(0);

      float fs[4];
#pragma unroll
      for (int r = 0; r < 4; ++r) {
        float cm = sacc[0][r];
#pragma unroll
        for (int f = 1; f < 8; ++f) cm = fmaxf(cm, sacc[f][r]);
#pragma unroll
        for (int mk = 1; mk < 16; mk <<= 1) cm = fmaxf(cm, __shfl_xor(cm, mk));
        float mn = fmaxf(m[rt][r], cm);
        fs[r] = __builtin_amdgcn_exp2f(m[rt][r] - mn);   // exp2 units
        m[rt][r] = mn;
        unsigned pa = lds_addr(&P[w][lg * 4 + r][lr]);
        float cs = 0.f;
#pragma unroll
        for (int f = 0; f < 8; ++f) {
          float p = __builtin_amdgcn_exp2f(sacc[f][r] - mn);
          asm volatile("ds_write_b16_d16_hi %0, %1 offset:%2"
                       :: "v"(pa), "v"(p), "i"(f * 32) : "memory");
          cs += p;
        }
#pragma unroll
        for (int mk = 1; mk < 16; mk <<= 1) cs += __shfl_xor(cs, mk);
        lsum[rt][r] = lsum[rt][r] * fs[r] + cs;
      }
#pragma unroll
      for (int fj = 0; fj < 4; ++fj)
#pragma unroll
        for (int r = 0; r < 4; ++r) oacc[rt][fj][r] *= fs[r];

      asm volatile("s_waitcnt lgkmcnt(0)" ::: "memory");
      __builtin_amdgcn_sched_barrier(0);
      __builtin_amdgcn_s_setprio(1);
#pragma unroll
      for (int ks = 0; ks < 4; ++ks) {
        s16x8 pa = *(const s16x8*)&P[w][lr][ks * 32 + lg * 8];
#pragma unroll
        for (int fj = 0; fj < 4; ++fj)
          oacc[rt][fj] = __builtin_amdgcn_mfma_f32_16x16x32_bf16(pa, vreg[ks * 4 + fj], oacc[rt][fj], 0, 0, 0);
      }
      __builtin_amdgcn_s_setprio(0);
    }

    if (c < 3) {
      // write to the INACTIVE buffer (no hazard; no barrier needed before)
#pragma unroll
      for (int it = 0; it < 4; ++it)
        *(s16x8*)&KS[cur ^ 1][it * 32 + srr][sdd] = kreg[it];
      __syncthreads();   // one barrier: writes visible + all reads of KS[cur] done
      cur ^= 1;
    }
  }

#pragma unroll
  for (int rt = 0; rt < 2; ++rt)
#pragma unroll
    for (int fj = 0; fj < 4; ++fj)
#pragma unroll
      for (int r = 0; r < 4; ++r) {
        int qrow = q0 + w * 32 + rt * 16 + lg * 4 + r;
        Out[((size_t)(n * 512 + qrow)) * 512 + h * 64 + fj * 16 + lr] =
            f2bf(oacc[rt][fj][r] / lsum[rt][r]);
      }
}

// ---------------- layernorm: 1 wave per 512-elem row, fused residual ------
// RES: add residual R (RBF selects bf16/f32); QIN: add onehot row
template<bool XBF, bool RES, bool RBF, bool QIN, bool OUTBF>
__global__ __launch_bounds__(256) void ln_kernel(const void* __restrict__ Xv,
    const void* __restrict__ Rv, const float* __restrict__ onehot,
    const float* __restrict__ g, const float* __restrict__ bb,
    void* __restrict__ outv) {
  int row = blockIdx.x * 4 + (threadIdx.x >> 6);
  int l = threadIdx.x & 63;
  size_t base = (size_t)row * 512 + l * 8;
  float v[8];
  if (XBF) {
    s16x8 xv = *(const s16x8*)((const unsigned short*)Xv + base);
#pragma unroll
    for (int j = 0; j < 8; ++j) v[j] = bf2f((unsigned short)xv[j]);
  } else {
    const float* X = (const float*)Xv;
    float4 x0 = *(const float4*)(X + base);
    float4 x1 = *(const float4*)(X + base + 4);
    v[0] = x0.x; v[1] = x0.y; v[2] = x0.z; v[3] = x0.w;
    v[4] = x1.x; v[5] = x1.y; v[6] = x1.z; v[7] = x1.w;
  }
  if (RES) {
    if (RBF) {
      s16x8 rv = *(const s16x8*)((const unsigned short*)Rv + base);
#pragma unroll
      for (int j = 0; j < 8; ++j) v[j] += bf2f((unsigned short)rv[j]);
    } else {
      const float* R = (const float*)Rv;
      float4 r0 = *(const float4*)(R + base);
      float4 r1 = *(const float4*)(R + base + 4);
      v[0] += r0.x; v[1] += r0.y; v[2] += r0.z; v[3] += r0.w;
      v[4] += r1.x; v[5] += r1.y; v[6] += r1.z; v[7] += r1.w;
    }
  }
  if (QIN) {
    size_t ob = (size_t)(row & 511) * 512 + l * 8;
    float4 o0 = *(const float4*)(onehot + ob);
    float4 o1 = *(const float4*)(onehot + ob + 4);
    v[0] += o0.x; v[1] += o0.y; v[2] += o0.z; v[3] += o0.w;
    v[4] += o1.x; v[5] += o1.y; v[6] += o1.z; v[7] += o1.w;
  }
  float s = 0.f, ss = 0.f;
#pragma unroll
  for (int j = 0; j < 8; ++j) { s += v[j]; ss += v[j] * v[j]; }
#pragma unroll
  for (int mk = 1; mk < 64; mk <<= 1) { s += __shfl_xor(s, mk); ss += __shfl_xor(ss, mk); }
  float mu = s * (1.f / 512.f);
  float inv = rsqrtf(ss * (1.f / 512.f) - mu * mu + 1e-5f);
#pragma unroll
  for (int j = 0; j < 8; ++j) {
    int e = l * 8 + j;
    float y = (v[j] - mu) * inv * g[e] + bb[e];
    if (OUTBF) ((unsigned short*)outv)[base + j] = f2bf(y);
    else ((float*)outv)[base + j] = y;
  }
}

extern "C" void kernel_launch(void* const* d_in, const int* in_sizes, int n_in,
                              void* d_out, int out_size, void* d_ws, size_t ws_size,
                              hipStream_t stream) {
  const float* value  = (const float*)d_in[0];
  const float* key_in = (const float*)d_in[1];
  const float* query  = (const float*)d_in[2];
  const int*   pi     = (const int*)d_in[3];
  const float* I_mat  = (const float*)d_in[4];
  const float* ohW    = (const float*)d_in[5];
  const float* ohb    = (const float*)d_in[6];
  const float* Wv     = (const float*)d_in[7];
  const float* Wk     = (const float*)d_in[8];
  const float* Wq     = (const float*)d_in[9];
  const float* Wo     = (const float*)d_in[10];
  const float* bo     = (const float*)d_in[11];
  const float* g1     = (const float*)d_in[12];
  const float* b1     = (const float*)d_in[13];
  const float* g2     = (const float*)d_in[14];
  const float* b2     = (const float*)d_in[15];
  const float* W1     = (const float*)d_in[16];
  const float* bf1    = (const float*)d_in[17];
  const float* W2     = (const float*)d_in[18];
  const float* bf2    = (const float*)d_in[19];

  char* ws = (char*)d_ws;
  const size_t MB = 1024 * 1024;
  unsigned short* q_p  = (unsigned short*)d_out;      // d_out as scratch
  unsigned short* k_p  = q_p + 16777216;
  unsigned short* vP     = (unsigned short*)(ws + 0);        // 32MB, fragment-packed
  unsigned short* attn_o = (unsigned short*)(ws + 32 * MB);  // 32MB
  unsigned short* x_b    = (unsigned short*)(ws + 64 * MB);  // 32MB
  unsigned short* ff1h   = (unsigned short*)(ws + 0);        // 64MB half (aliases vP/attn_o)
  float*          onehot = (float*)(ws + 96 * MB);           // 1MB
  unsigned short* Wv_b   = (unsigned short*)(ws + 97 * MB);
  unsigned short* Wk_b   = Wv_b + 4096;
  unsigned short* Wq_b   = Wk_b + 4096;
  unsigned short* Wop    = Wq_b + 4096;      // 512KB packed
  unsigned short* W1p    = Wop + 262144;     // 2MB packed
  unsigned short* W2p    = W1p + 1048576;    // 2MB packed

  prep_kernel<<<1667, 256, 0, stream>>>(pi, I_mat, ohW, ohb, onehot,
      Wv, Wk, Wq, Wv_b, Wk_b, Wq_b, Wo, W1, W2, Wop, W1p, W2p);

  proj_all<<<12288, 256, 0, stream>>>(value, key_in, query,
      Wv_b, Wk_b, Wq_b, onehot, vP, k_p, q_p);

  attn_kernel<<<2048, 256, 0, stream>>>(q_p, k_p, vP, attn_o);

  // Wo: x_b(bf16) = attn_o @ Wo + bo
  gemmF<false, true, false><<<1024, 256, 0, stream>>>(
      attn_o, 512, Wop, 32, 0, bo, x_b, nullptr, 512, 32768, 512, 4);
  // LN1 in place on x_b, residual = query + onehot
  ln_kernel<true, true, false, true, true><<<8192, 256, 0, stream>>>(
      x_b, query, onehot, g1, b1, x_b);

  // FFN split over 2 row-halves (M=16384 each); FFN2 fuses +x residual
  for (int hf = 0; hf < 2; ++hf) {
    const unsigned short* xh = x_b + (size_t)hf * 16384 * 512;
    gemmF<true, true, false><<<2048, 256, 0, stream>>>(
        xh, 512, W1p, 128, 0, bf1, ff1h, nullptr, 2048, 16384, 512, 16);
    gemmF<false, false, true><<<512, 256, 0, stream>>>(
        ff1h, 2048, W2p, 32, 0, bf2, (float*)d_out + (size_t)hf * 16384 * 512,
        xh, 512, 16384, 2048, 4);
  }
  // LN2: X = d_out f32 (residual already added) -> d_out in place
  ln_kernel<false, false, false, false, false><<<8192, 256, 0, stream>>>(
      d_out, nullptr, nullptr, g2, b2, d_out);
}